// Round 1
// baseline (253.652 us; speedup 1.0000x reference)
//
#include <hip/hip_runtime.h>
#include <math.h>

#define N_ENT 20000
#define D 200
#define NB 8
#define NM 5

// ws layout (in floats)
#define Q_OFF     0         // 8 vec * 8 b * 200 d = 12800 floats (51.2 KB)
#define PART_OFF  12800     // 625 blocks * 40 pairs * 4 stats = 100000 floats
#define C_OFF     112800    // 40 floats: c[m][b]
#define CONST_OFF 112840    // 8 floats
#define S_OFF     114688    // 5*8*20000 = 800000 floats (3.2 MB), 16B aligned
#define NBLK_MAIN 625       // 625 * 32 entities = 20000 exactly

#define COMP(v,j) ((j)==0 ? (v).x : (j)==1 ? (v).y : (j)==2 ? (v).z : (v).w)

// ---------------- K_q: build 8 per-b query vectors into ws ----------------
__global__ __launch_bounds__(256) void k_q(
    const int* __restrict__ batch, const float* __restrict__ eemb,
    const float* __restrict__ remb,
    const float* __restrict__ ce_re, const float* __restrict__ ce_im,
    const float* __restrict__ cr_re, const float* __restrict__ cr_im,
    const float* __restrict__ de, const float* __restrict__ dr,
    const float* __restrict__ ke, const float* __restrict__ kr,
    const float* __restrict__ se_h, const float* __restrict__ se_t,
    const float* __restrict__ sr, const float* __restrict__ sr_inv,
    float* __restrict__ ws)
{
    int b = blockIdx.x;
    int d = threadIdx.x;
    if (d >= D) return;
    int h = batch[b*48 + 0];   // batch[b][0][0]
    int r = batch[b*48 + 2];   // batch[b][0][2]
    float* q = ws + Q_OFF;

    float her = eemb[h*400 + d];
    float hei = eemb[h*400 + 200 + d];
    float ph  = remb[r*200 + d];
    float cph = cosf(ph), sph = sinf(ph);
    q[(0*8 + b)*200 + d] = her*cph - hei*sph;          // p_re
    q[(1*8 + b)*200 + d] = her*sph + hei*cph;          // p_im

    float cer = ce_re[h*200+d], cei = ce_im[h*200+d];
    float crr = cr_re[r*200+d], cri = cr_im[r*200+d];
    q[(2*8 + b)*200 + d] = cer*crr - cei*cri;          // s_re
    q[(3*8 + b)*200 + d] = cer*cri + cei*crr;          // s_im

    q[(4*8 + b)*200 + d] = ke[h*200+d] * kr[r*200+d];  // kdg
    q[(5*8 + b)*200 + d] = de[h*200+d] * dr[r*200+d];  // distmult
    q[(6*8 + b)*200 + d] = se_h[h*200+d] * sr[r*200+d];     // pairs with se_t[e]
    q[(7*8 + b)*200 + d] = se_t[h*200+d] * sr_inv[r*200+d]; // pairs with se_h[e]
}

// ---------------- K_main: all 5 raw scores + per-block row stats ----------------
// block = 64 threads = 1 wave: lane = el*8 + b; el in [0,8) entity-groups, b in [0,8)
// each thread: 4 consecutive entities, one b, all 5 models, full D.
__global__ __launch_bounds__(64) void k_main(
    const float* __restrict__ eemb, const float* __restrict__ ce_re,
    const float* __restrict__ ce_im, const float* __restrict__ ke,
    const float* __restrict__ de, const float* __restrict__ se_h,
    const float* __restrict__ se_t, float* __restrict__ ws)
{
    const float* q = ws + Q_OFF;
    float* S    = ws + S_OFF;
    float* part = ws + PART_OFF;

    int lane = threadIdx.x;
    int b  = lane & 7;
    int el = lane >> 3;
    int e0 = blockIdx.x * 32 + el * 4;

    float acc[NM][4];
#pragma unroll
    for (int m = 0; m < NM; ++m)
#pragma unroll
        for (int ep = 0; ep < 4; ++ep) acc[m][ep] = 0.f;

    const float* qb = q + b*200;

    for (int d0 = 0; d0 < D; d0 += 4) {
        float4 pre = *(const float4*)(qb + 0*1600 + d0);
        float4 pim = *(const float4*)(qb + 1*1600 + d0);
        float4 sre = *(const float4*)(qb + 2*1600 + d0);
        float4 sim = *(const float4*)(qb + 3*1600 + d0);
        float4 qk  = *(const float4*)(qb + 4*1600 + d0);
        float4 qd  = *(const float4*)(qb + 5*1600 + d0);
        float4 q6  = *(const float4*)(qb + 6*1600 + d0);
        float4 q7  = *(const float4*)(qb + 7*1600 + d0);
#pragma unroll
        for (int ep = 0; ep < 4; ++ep) {
            int e = e0 + ep;
            const float* er = eemb + e*400 + d0;
            float4 tre = *(const float4*)(er);
            float4 tim = *(const float4*)(er + 200);
            float4 cre = *(const float4*)(ce_re + e*200 + d0);
            float4 cim = *(const float4*)(ce_im + e*200 + d0);
            float4 kee = *(const float4*)(ke    + e*200 + d0);
            float4 dee = *(const float4*)(de    + e*200 + d0);
            float4 set = *(const float4*)(se_t  + e*200 + d0);
            float4 seh = *(const float4*)(se_h  + e*200 + d0);
#pragma unroll
            for (int j = 0; j < 4; ++j) {
                float dre = COMP(pre,j) - COMP(tre,j);
                float dii = COMP(pim,j) - COMP(tim,j);
                acc[0][ep] += __builtin_amdgcn_sqrtf(fmaf(dre,dre,dii*dii));
                acc[1][ep] = fmaf(COMP(sre,j), COMP(cre,j),
                             fmaf(COMP(sim,j), COMP(cim,j), acc[1][ep]));
                acc[2][ep] = fmaf(COMP(qk,j), COMP(kee,j), acc[2][ep]);
                acc[3][ep] = fmaf(COMP(qd,j), COMP(dee,j), acc[3][ep]);
                acc[4][ep] = fmaf(COMP(q6,j), COMP(set,j),
                             fmaf(COMP(q7,j), COMP(seh,j), acc[4][ep]));
            }
        }
    }

    // finalize, store raw scores, per-thread stats
    float mn[NM], mx[NM], sm[NM], sq[NM];
#pragma unroll
    for (int m = 0; m < NM; ++m) { mn[m]=INFINITY; mx[m]=-INFINITY; sm[m]=0.f; sq[m]=0.f; }
#pragma unroll
    for (int ep = 0; ep < 4; ++ep) {
        int e = e0 + ep;
        float vals[NM];
        vals[0] = -acc[0][ep];
        vals[1] = acc[1][ep];
        vals[2] = acc[2][ep];
        vals[3] = acc[3][ep];
        vals[4] = 0.5f * acc[4][ep];
#pragma unroll
        for (int m = 0; m < NM; ++m) {
            float s = vals[m];
            S[(m*8 + b)*N_ENT + e] = s;
            mn[m] = fminf(mn[m], s);
            mx[m] = fmaxf(mx[m], s);
            sm[m] += s;
            sq[m] = fmaf(s, s, sq[m]);
        }
    }

    // reduce over the 8 entity-groups (lanes differing in bits 3..5)
#pragma unroll
    for (int off = 8; off < 64; off <<= 1) {
#pragma unroll
        for (int m = 0; m < NM; ++m) {
            mn[m] = fminf(mn[m], __shfl_xor(mn[m], off, 64));
            mx[m] = fmaxf(mx[m], __shfl_xor(mx[m], off, 64));
            sm[m] += __shfl_xor(sm[m], off, 64);
            sq[m] += __shfl_xor(sq[m], off, 64);
        }
    }
    if (el == 0) {
#pragma unroll
        for (int m = 0; m < NM; ++m) {
            float4 v = make_float4(mn[m], mx[m], sm[m], sq[m]);
            *(float4*)(part + (blockIdx.x*40 + m*8 + b)*4) = v;
        }
    }
}

// ---------------- K_stats: final stats + features + 5-expert MLP + coeffs ----------------
__global__ __launch_bounds__(320) void k_stats(
    const float* __restrict__ W0, const float* __restrict__ b0,
    const float* __restrict__ W1, const float* __restrict__ b1,
    const float* __restrict__ W2, const float* __restrict__ b2,
    const float* __restrict__ W3, const float* __restrict__ b3,
    float* __restrict__ ws)
{
    const float* part = ws + PART_OFF;
    __shared__ float  redmn[8][40], redmx[8][40];
    __shared__ double redsm[8][40], redsq[8][40];
    __shared__ float  feat[NB][10];
    __shared__ float  mnS[NM][NB], rngS[NM][NB];
    __shared__ float  xA[NM][NB][64], xB[NM][NB][64];
    __shared__ float  wS[NM][NB];

    int t = threadIdx.x;
    {   // sliced reduction over 625 block-partials
        int p = t % 40, sl = t / 40;  // sl in [0,8)
        float mn = INFINITY, mx = -INFINITY; double sm = 0.0, sq = 0.0;
        for (int blk = sl; blk < NBLK_MAIN; blk += 8) {
            float4 v = *(const float4*)(part + (blk*40 + p)*4);
            mn = fminf(mn, v.x); mx = fmaxf(mx, v.y);
            sm += (double)v.z;   sq += (double)v.w;
        }
        redmn[sl][p] = mn; redmx[sl][p] = mx; redsm[sl][p] = sm; redsq[sl][p] = sq;
    }
    __syncthreads();
    if (t < 40) {
        float mn = INFINITY, mx = -INFINITY; double sm = 0.0, sq = 0.0;
        for (int sl = 0; sl < 8; ++sl) {
            mn = fminf(mn, redmn[sl][t]); mx = fmaxf(mx, redmx[sl][t]);
            sm += redsm[sl][t];           sq += redsq[sl][t];
        }
        int m = t / 8, b = t % 8;
        float  rng  = mx - mn;
        double mean = sm / (double)N_ENT;
        float  md   = 1.0f - (float)((mean - (double)mn) / (double)rng);
        double va   = (sq - sm*sm/(double)N_ENT) / (double)(N_ENT - 1);
        float  vn   = (float)(va / ((double)rng * (double)rng));
        feat[b][2*m]   = md;
        feat[b][2*m+1] = vn;
        mnS[m][b] = mn; rngS[m][b] = rng;
    }
    __syncthreads();

    int ex = t / 64, o = t % 64;   // 5 experts x 64 neurons
    for (int b = 0; b < NB; ++b) { // layer 0 (no relu)
        float a = b0[ex*64 + o];
#pragma unroll
        for (int i = 0; i < 10; ++i) a = fmaf(feat[b][i], W0[ex*640 + i*64 + o], a);
        xA[ex][b][o] = a;
    }
    __syncthreads();
    for (int b = 0; b < NB; ++b) { // layer 1 + relu
        float a = b1[ex*64 + o];
        for (int i = 0; i < 64; ++i) a = fmaf(xA[ex][b][i], W1[ex*4096 + i*64 + o], a);
        xB[ex][b][o] = fmaxf(a, 0.f);
    }
    __syncthreads();
    for (int b = 0; b < NB; ++b) { // layer 2 + relu
        float a = b2[ex*64 + o];
        for (int i = 0; i < 64; ++i) a = fmaf(xB[ex][b][i], W2[ex*4096 + i*64 + o], a);
        xA[ex][b][o] = fmaxf(a, 0.f);
    }
    __syncthreads();
    if (o == 0) {                  // layer 3 + relu -> w[expert][b]
        for (int b = 0; b < NB; ++b) {
            float a = b3[ex];
            for (int i = 0; i < 64; ++i) a = fmaf(xA[ex][b][i], W3[ex*64 + i], a);
            wS[ex][b] = fmaxf(a, 0.f);
        }
    }
    __syncthreads();
    if (t < 8) {                   // per-b weight norm + affine coefficients
        int b = t;
        float wm = 0.f;
        for (int m = 0; m < NM; ++m) wm = fmaxf(wm, fabsf(wS[m][b]));
        float cst = 0.f;
        for (int m = 0; m < NM; ++m) {
            float w  = wS[m][b] / wm;
            float cc = w / rngS[m][b];
            ws[C_OFF + m*8 + b] = cc;
            cst -= cc * mnS[m][b];
        }
        ws[CONST_OFF + b] = cst;
    }
}

// ---------------- K_combine: out[b,e] = sum_m c[m,b]*S[m,b,e] + const[b] ----------------
__global__ __launch_bounds__(256) void k_comb(const float* __restrict__ ws,
                                              float* __restrict__ out)
{
    int t = blockIdx.x * 256 + threadIdx.x;
    if (t >= NB * (N_ENT/4)) return;
    int b = t / (N_ENT/4);
    int e = (t % (N_ENT/4)) * 4;
    const float* S = ws + S_OFF;
    float c0 = ws[C_OFF +  0 + b], c1 = ws[C_OFF +  8 + b], c2 = ws[C_OFF + 16 + b];
    float c3 = ws[C_OFF + 24 + b], c4 = ws[C_OFF + 32 + b];
    float cst = ws[CONST_OFF + b];
    float4 s0 = *(const float4*)(S + (0*8 + b)*N_ENT + e);
    float4 s1 = *(const float4*)(S + (1*8 + b)*N_ENT + e);
    float4 s2 = *(const float4*)(S + (2*8 + b)*N_ENT + e);
    float4 s3 = *(const float4*)(S + (3*8 + b)*N_ENT + e);
    float4 s4 = *(const float4*)(S + (4*8 + b)*N_ENT + e);
    float4 o4;
    o4.x = fmaf(c0,s0.x, fmaf(c1,s1.x, fmaf(c2,s2.x, fmaf(c3,s3.x, fmaf(c4,s4.x, cst)))));
    o4.y = fmaf(c0,s0.y, fmaf(c1,s1.y, fmaf(c2,s2.y, fmaf(c3,s3.y, fmaf(c4,s4.y, cst)))));
    o4.z = fmaf(c0,s0.z, fmaf(c1,s1.z, fmaf(c2,s2.z, fmaf(c3,s3.z, fmaf(c4,s4.z, cst)))));
    o4.w = fmaf(c0,s0.w, fmaf(c1,s1.w, fmaf(c2,s2.w, fmaf(c3,s3.w, fmaf(c4,s4.w, cst)))));
    *(float4*)(out + b*N_ENT + e) = o4;
}

extern "C" void kernel_launch(void* const* d_in, const int* in_sizes, int n_in,
                              void* d_out, int out_size, void* d_ws, size_t ws_size,
                              hipStream_t stream)
{
    const int*   batch  = (const int*)  d_in[0];
    const float* eemb   = (const float*)d_in[1];
    const float* remb   = (const float*)d_in[2];
    const float* ce_re  = (const float*)d_in[3];
    const float* ce_im  = (const float*)d_in[4];
    const float* cr_re  = (const float*)d_in[5];
    const float* cr_im  = (const float*)d_in[6];
    const float* de     = (const float*)d_in[7];
    const float* dr     = (const float*)d_in[8];
    const float* ke     = (const float*)d_in[9];
    const float* kr     = (const float*)d_in[10];
    const float* se_h   = (const float*)d_in[11];
    const float* se_t   = (const float*)d_in[12];
    const float* sr     = (const float*)d_in[13];
    const float* sr_inv = (const float*)d_in[14];
    const float* W0 = (const float*)d_in[15];
    const float* b0 = (const float*)d_in[16];
    const float* W1 = (const float*)d_in[17];
    const float* b1 = (const float*)d_in[18];
    const float* W2 = (const float*)d_in[19];
    const float* b2 = (const float*)d_in[20];
    const float* W3 = (const float*)d_in[21];
    const float* b3 = (const float*)d_in[22];
    float* ws  = (float*)d_ws;
    float* out = (float*)d_out;

    k_q    <<<8, 256, 0, stream>>>(batch, eemb, remb, ce_re, ce_im, cr_re, cr_im,
                                   de, dr, ke, kr, se_h, se_t, sr, sr_inv, ws);
    k_main <<<NBLK_MAIN, 64, 0, stream>>>(eemb, ce_re, ce_im, ke, de, se_h, se_t, ws);
    k_stats<<<1, 320, 0, stream>>>(W0, b0, W1, b1, W2, b2, W3, b3, ws);
    k_comb <<<(NB*(N_ENT/4) + 255)/256, 256, 0, stream>>>(ws, out);
}

// Round 2
// 150.216 us; speedup vs baseline: 1.6886x; 1.6886x over previous
//
#include <hip/hip_runtime.h>
#include <math.h>

#define N_ENT 20000
#define D 200
#define NB 8
#define NM 5
#define NBLK_MAIN 1250   // 16 entities per block

// ws layout (in floats)
#define Q_OFF     0        // 8 vec * 8 b * 200 = 12800
#define PART_OFF  12800    // 1250 blocks * 40 pairs * 4 = 200000
#define MNMX_OFF  212800   // 40 * 2 floats
#define STATD_OFF 212880   // 40 * 2 doubles = 160 floats (8B aligned: even offset)
#define C_OFF     213040   // 40
#define CONST_OFF 213080   // 8
#define S_OFF     213088   // 5*8*20000 = 800000 (16B aligned: off%4==0)

#define COMP(v,j) ((j)==0 ? (v).x : (j)==1 ? (v).y : (j)==2 ? (v).z : (v).w)

// ---------------- K_q: build 8 per-b query vectors into ws ----------------
__global__ __launch_bounds__(256) void k_q(
    const int* __restrict__ batch, const float* __restrict__ eemb,
    const float* __restrict__ remb,
    const float* __restrict__ ce_re, const float* __restrict__ ce_im,
    const float* __restrict__ cr_re, const float* __restrict__ cr_im,
    const float* __restrict__ de, const float* __restrict__ dr,
    const float* __restrict__ ke, const float* __restrict__ kr,
    const float* __restrict__ se_h, const float* __restrict__ se_t,
    const float* __restrict__ sr, const float* __restrict__ sr_inv,
    float* __restrict__ ws)
{
    int b = blockIdx.x;
    int d = threadIdx.x;
    if (d >= D) return;
    int h = batch[b*48 + 0];
    int r = batch[b*48 + 2];
    float* q = ws + Q_OFF;

    float her = eemb[h*400 + d];
    float hei = eemb[h*400 + 200 + d];
    float ph  = remb[r*200 + d];
    float cph = cosf(ph), sph = sinf(ph);
    q[(0*8 + b)*200 + d] = her*cph - hei*sph;          // p_re
    q[(1*8 + b)*200 + d] = her*sph + hei*cph;          // p_im

    float cer = ce_re[h*200+d], cei = ce_im[h*200+d];
    float crr = cr_re[r*200+d], cri = cr_im[r*200+d];
    q[(2*8 + b)*200 + d] = cer*crr - cei*cri;          // s_re
    q[(3*8 + b)*200 + d] = cer*cri + cei*crr;          // s_im

    q[(4*8 + b)*200 + d] = ke[h*200+d] * kr[r*200+d];
    q[(5*8 + b)*200 + d] = de[h*200+d] * dr[r*200+d];
    q[(6*8 + b)*200 + d] = se_h[h*200+d] * sr[r*200+d];
    q[(7*8 + b)*200 + d] = se_t[h*200+d] * sr_inv[r*200+d];
}

// ---------------- K_main ----------------
// 256 threads = 4 waves; wave lane = dh*32 + el*8 + b.
// thread: entity e = blk*16 + wave*4 + el, batch b, d-half dh (100 floats), all 5 models.
__global__ __launch_bounds__(256) void k_main(
    const float* __restrict__ eemb, const float* __restrict__ ce_re,
    const float* __restrict__ ce_im, const float* __restrict__ ke,
    const float* __restrict__ de, const float* __restrict__ se_h,
    const float* __restrict__ se_t, float* __restrict__ ws)
{
    const float* q = ws + Q_OFF;
    float* S    = ws + S_OFF;
    float* part = ws + PART_OFF;
    __shared__ float red[4][40][4];

    int tid  = threadIdx.x;
    int wave = tid >> 6, lane = tid & 63;
    int dh = lane >> 5, el = (lane >> 3) & 3, b = lane & 7;
    int e  = blockIdx.x * 16 + wave * 4 + el;
    int dbase = dh * 100;

    const float* qb  = q + b*200 + dbase;
    const float* er0 = eemb + e*400 + dbase;        // t_re
    const float* er1 = er0 + 200;                   // t_im
    const float* pcr = ce_re + e*200 + dbase;
    const float* pci = ce_im + e*200 + dbase;
    const float* pke = ke    + e*200 + dbase;
    const float* pde = de    + e*200 + dbase;
    const float* pst = se_t  + e*200 + dbase;
    const float* psh = se_h  + e*200 + dbase;

    float a0=0.f, a1=0.f, a2=0.f, a3=0.f, a4=0.f;

    for (int i = 0; i < 100; i += 4) {
        float4 pre = *(const float4*)(qb + 0*1600 + i);
        float4 pim = *(const float4*)(qb + 1*1600 + i);
        float4 sre = *(const float4*)(qb + 2*1600 + i);
        float4 sim = *(const float4*)(qb + 3*1600 + i);
        float4 qk  = *(const float4*)(qb + 4*1600 + i);
        float4 qd  = *(const float4*)(qb + 5*1600 + i);
        float4 q6  = *(const float4*)(qb + 6*1600 + i);
        float4 q7  = *(const float4*)(qb + 7*1600 + i);
        float4 tre = *(const float4*)(er0 + i);
        float4 tim = *(const float4*)(er1 + i);
        float4 cre = *(const float4*)(pcr + i);
        float4 cim = *(const float4*)(pci + i);
        float4 kee = *(const float4*)(pke + i);
        float4 dee = *(const float4*)(pde + i);
        float4 set = *(const float4*)(pst + i);
        float4 seh = *(const float4*)(psh + i);
#pragma unroll
        for (int j = 0; j < 4; ++j) {
            float dre = COMP(pre,j) - COMP(tre,j);
            float dii = COMP(pim,j) - COMP(tim,j);
            a0 += __builtin_amdgcn_sqrtf(fmaf(dre,dre,dii*dii));
            a1 = fmaf(COMP(sre,j), COMP(cre,j), fmaf(COMP(sim,j), COMP(cim,j), a1));
            a2 = fmaf(COMP(qk,j),  COMP(kee,j), a2);
            a3 = fmaf(COMP(qd,j),  COMP(dee,j), a3);
            a4 = fmaf(COMP(q6,j),  COMP(set,j), fmaf(COMP(q7,j), COMP(seh,j), a4));
        }
    }

    // combine the two d-halves (partner lane differs only in bit 5)
    a0 += __shfl_xor(a0, 32, 64);
    a1 += __shfl_xor(a1, 32, 64);
    a2 += __shfl_xor(a2, 32, 64);
    a3 += __shfl_xor(a3, 32, 64);
    a4 += __shfl_xor(a4, 32, 64);

    float vals[NM];
    vals[0] = -a0; vals[1] = a1; vals[2] = a2; vals[3] = a3; vals[4] = 0.5f * a4;

    if (dh == 0) {
#pragma unroll
        for (int m = 0; m < NM; ++m) S[(m*8 + b)*N_ENT + e] = vals[m];
    }

    // per-thread -> per-wave (4 entities) stats
    float mn[NM], mx[NM], sm[NM], sq[NM];
#pragma unroll
    for (int m = 0; m < NM; ++m) {
        mn[m] = vals[m]; mx[m] = vals[m]; sm[m] = vals[m]; sq[m] = vals[m]*vals[m];
    }
#pragma unroll
    for (int off = 8; off <= 16; off <<= 1) {
#pragma unroll
        for (int m = 0; m < NM; ++m) {
            mn[m] = fminf(mn[m], __shfl_xor(mn[m], off, 64));
            mx[m] = fmaxf(mx[m], __shfl_xor(mx[m], off, 64));
            sm[m] += __shfl_xor(sm[m], off, 64);
            sq[m] += __shfl_xor(sq[m], off, 64);
        }
    }
    if (lane < 8) {   // dh==0, el==0; lane == b
#pragma unroll
        for (int m = 0; m < NM; ++m) {
            red[wave][m*8 + b][0] = mn[m];
            red[wave][m*8 + b][1] = mx[m];
            red[wave][m*8 + b][2] = sm[m];
            red[wave][m*8 + b][3] = sq[m];
        }
    }
    __syncthreads();
    if (tid < 40) {   // combine the block's 4 waves (16 entities)
        float fmn = INFINITY, fmx = -INFINITY, fsm = 0.f, fsq = 0.f;
#pragma unroll
        for (int w = 0; w < 4; ++w) {
            fmn = fminf(fmn, red[w][tid][0]);
            fmx = fmaxf(fmx, red[w][tid][1]);
            fsm += red[w][tid][2];
            fsq += red[w][tid][3];
        }
        *(float4*)(part + (blockIdx.x*40 + tid)*4) = make_float4(fmn, fmx, fsm, fsq);
    }
}

// ---------------- K_red: reduce 1250 partials per (m,b) pair ----------------
__global__ __launch_bounds__(64) void k_red(float* __restrict__ ws)
{
    const float* part = ws + PART_OFF;
    int p = blockIdx.x;      // 0..39 = m*8+b
    int l = threadIdx.x;
    float mn = INFINITY, mx = -INFINITY;
    double sm = 0.0, sq = 0.0;
    for (int blk = l; blk < NBLK_MAIN; blk += 64) {
        float4 v = *(const float4*)(part + (blk*40 + p)*4);
        mn = fminf(mn, v.x); mx = fmaxf(mx, v.y);
        sm += (double)v.z;   sq += (double)v.w;
    }
#pragma unroll
    for (int off = 1; off < 64; off <<= 1) {
        mn = fminf(mn, __shfl_xor(mn, off, 64));
        mx = fmaxf(mx, __shfl_xor(mx, off, 64));
        sm += __shfl_xor(sm, off, 64);
        sq += __shfl_xor(sq, off, 64);
    }
    if (l == 0) {
        ws[MNMX_OFF + p*2]     = mn;
        ws[MNMX_OFF + p*2 + 1] = mx;
        double* sd = (double*)(ws + STATD_OFF);
        sd[p*2]     = sm;
        sd[p*2 + 1] = sq;
    }
}

// ---------------- K_mlp: features + 5-expert MLP + affine coefficients ----------------
__global__ __launch_bounds__(320) void k_mlp(
    const float* __restrict__ W0, const float* __restrict__ b0,
    const float* __restrict__ W1, const float* __restrict__ b1,
    const float* __restrict__ W2, const float* __restrict__ b2,
    const float* __restrict__ W3, const float* __restrict__ b3,
    float* __restrict__ ws)
{
    __shared__ float feat[NB][10];
    __shared__ float mnS[NM][NB], rngS[NM][NB];
    __shared__ float xA[NM][NB][64], xB[NM][NB][64];
    __shared__ float wS[NM][NB];

    int t = threadIdx.x;
    if (t < 40) {
        int m = t / 8, b = t % 8;
        float  mn = ws[MNMX_OFF + t*2];
        float  mx = ws[MNMX_OFF + t*2 + 1];
        const double* sd = (const double*)(ws + STATD_OFF);
        double sm = sd[t*2], sq = sd[t*2 + 1];
        float  rng  = mx - mn;
        double mean = sm / (double)N_ENT;
        float  md   = 1.0f - (float)((mean - (double)mn) / (double)rng);
        double va   = (sq - sm*sm/(double)N_ENT) / (double)(N_ENT - 1);
        float  vn   = (float)(va / ((double)rng * (double)rng));
        feat[b][2*m]   = md;
        feat[b][2*m+1] = vn;
        mnS[m][b] = mn; rngS[m][b] = rng;
    }
    __syncthreads();

    int ex = t / 64, o = t % 64;
    for (int b = 0; b < NB; ++b) {
        float a = b0[ex*64 + o];
#pragma unroll
        for (int i = 0; i < 10; ++i) a = fmaf(feat[b][i], W0[ex*640 + i*64 + o], a);
        xA[ex][b][o] = a;
    }
    __syncthreads();
    for (int b = 0; b < NB; ++b) {
        float a = b1[ex*64 + o];
        for (int i = 0; i < 64; ++i) a = fmaf(xA[ex][b][i], W1[ex*4096 + i*64 + o], a);
        xB[ex][b][o] = fmaxf(a, 0.f);
    }
    __syncthreads();
    for (int b = 0; b < NB; ++b) {
        float a = b2[ex*64 + o];
        for (int i = 0; i < 64; ++i) a = fmaf(xB[ex][b][i], W2[ex*4096 + i*64 + o], a);
        xA[ex][b][o] = fmaxf(a, 0.f);
    }
    __syncthreads();
    if (o == 0) {
        for (int b = 0; b < NB; ++b) {
            float a = b3[ex];
            for (int i = 0; i < 64; ++i) a = fmaf(xA[ex][b][i], W3[ex*64 + i], a);
            wS[ex][b] = fmaxf(a, 0.f);
        }
    }
    __syncthreads();
    if (t < 8) {
        int b = t;
        float wm = 0.f;
        for (int m = 0; m < NM; ++m) wm = fmaxf(wm, fabsf(wS[m][b]));
        float cst = 0.f;
        for (int m = 0; m < NM; ++m) {
            float w  = wS[m][b] / wm;
            float cc = w / rngS[m][b];
            ws[C_OFF + m*8 + b] = cc;
            cst -= cc * mnS[m][b];
        }
        ws[CONST_OFF + b] = cst;
    }
}

// ---------------- K_combine ----------------
__global__ __launch_bounds__(256) void k_comb(const float* __restrict__ ws,
                                              float* __restrict__ out)
{
    int t = blockIdx.x * 256 + threadIdx.x;
    if (t >= NB * (N_ENT/4)) return;
    int b = t / (N_ENT/4);
    int e = (t % (N_ENT/4)) * 4;
    const float* S = ws + S_OFF;
    float c0 = ws[C_OFF +  0 + b], c1 = ws[C_OFF +  8 + b], c2 = ws[C_OFF + 16 + b];
    float c3 = ws[C_OFF + 24 + b], c4 = ws[C_OFF + 32 + b];
    float cst = ws[CONST_OFF + b];
    float4 s0 = *(const float4*)(S + (0*8 + b)*N_ENT + e);
    float4 s1 = *(const float4*)(S + (1*8 + b)*N_ENT + e);
    float4 s2 = *(const float4*)(S + (2*8 + b)*N_ENT + e);
    float4 s3 = *(const float4*)(S + (3*8 + b)*N_ENT + e);
    float4 s4 = *(const float4*)(S + (4*8 + b)*N_ENT + e);
    float4 o4;
    o4.x = fmaf(c0,s0.x, fmaf(c1,s1.x, fmaf(c2,s2.x, fmaf(c3,s3.x, fmaf(c4,s4.x, cst)))));
    o4.y = fmaf(c0,s0.y, fmaf(c1,s1.y, fmaf(c2,s2.y, fmaf(c3,s3.y, fmaf(c4,s4.y, cst)))));
    o4.z = fmaf(c0,s0.z, fmaf(c1,s1.z, fmaf(c2,s2.z, fmaf(c3,s3.z, fmaf(c4,s4.z, cst)))));
    o4.w = fmaf(c0,s0.w, fmaf(c1,s1.w, fmaf(c2,s2.w, fmaf(c3,s3.w, fmaf(c4,s4.w, cst)))));
    *(float4*)(out + b*N_ENT + e) = o4;
}

extern "C" void kernel_launch(void* const* d_in, const int* in_sizes, int n_in,
                              void* d_out, int out_size, void* d_ws, size_t ws_size,
                              hipStream_t stream)
{
    const int*   batch  = (const int*)  d_in[0];
    const float* eemb   = (const float*)d_in[1];
    const float* remb   = (const float*)d_in[2];
    const float* ce_re  = (const float*)d_in[3];
    const float* ce_im  = (const float*)d_in[4];
    const float* cr_re  = (const float*)d_in[5];
    const float* cr_im  = (const float*)d_in[6];
    const float* de     = (const float*)d_in[7];
    const float* dr     = (const float*)d_in[8];
    const float* ke     = (const float*)d_in[9];
    const float* kr     = (const float*)d_in[10];
    const float* se_h   = (const float*)d_in[11];
    const float* se_t   = (const float*)d_in[12];
    const float* sr     = (const float*)d_in[13];
    const float* sr_inv = (const float*)d_in[14];
    const float* W0 = (const float*)d_in[15];
    const float* b0 = (const float*)d_in[16];
    const float* W1 = (const float*)d_in[17];
    const float* b1 = (const float*)d_in[18];
    const float* W2 = (const float*)d_in[19];
    const float* b2 = (const float*)d_in[20];
    const float* W3 = (const float*)d_in[21];
    const float* b3 = (const float*)d_in[22];
    float* ws  = (float*)d_ws;
    float* out = (float*)d_out;

    k_q    <<<8, 256, 0, stream>>>(batch, eemb, remb, ce_re, ce_im, cr_re, cr_im,
                                   de, dr, ke, kr, se_h, se_t, sr, sr_inv, ws);
    k_main <<<NBLK_MAIN, 256, 0, stream>>>(eemb, ce_re, ce_im, ke, de, se_h, se_t, ws);
    k_red  <<<40, 64, 0, stream>>>(ws);
    k_mlp  <<<1, 320, 0, stream>>>(W0, b0, W1, b1, W2, b2, W3, b3, ws);
    k_comb <<<(NB*(N_ENT/4) + 255)/256, 256, 0, stream>>>(ws, out);
}

// Round 3
// 108.674 us; speedup vs baseline: 2.3341x; 1.3823x over previous
//
#include <hip/hip_runtime.h>
#include <math.h>

#define N_ENT 20000
#define D 200
#define NB 8
#define NM 5
#define NBLK_MAIN 1250   // 16 entities per block

// ws layout (in floats) — identical to round 1
#define Q_OFF     0        // 8 vec * 8 b * 200 = 12800
#define PART_OFF  12800    // 1250 blocks * 40 pairs * 4 = 200000
#define MNMX_OFF  212800   // 40 * 2 floats
#define STATD_OFF 212880   // 40 * 2 doubles = 160 floats
#define C_OFF     213040   // 40
#define CONST_OFF 213080   // 8
#define S_OFF     213088   // 5*8*20000 = 800000

#define COMP(v,j) ((j)==0 ? (v).x : (j)==1 ? (v).y : (j)==2 ? (v).z : (v).w)
#define LD4(p) (*(const float4*)(p))

// ---------------- K_q: build 8 per-b query vectors into ws ----------------
__global__ __launch_bounds__(256) void k_q(
    const int* __restrict__ batch, const float* __restrict__ eemb,
    const float* __restrict__ remb,
    const float* __restrict__ ce_re, const float* __restrict__ ce_im,
    const float* __restrict__ cr_re, const float* __restrict__ cr_im,
    const float* __restrict__ de, const float* __restrict__ dr,
    const float* __restrict__ ke, const float* __restrict__ kr,
    const float* __restrict__ se_h, const float* __restrict__ se_t,
    const float* __restrict__ sr, const float* __restrict__ sr_inv,
    float* __restrict__ ws)
{
    int b = blockIdx.x;
    int d = threadIdx.x;
    if (d >= D) return;
    int h = batch[b*48 + 0];
    int r = batch[b*48 + 2];
    float* q = ws + Q_OFF;

    float her = eemb[h*400 + d];
    float hei = eemb[h*400 + 200 + d];
    float ph  = remb[r*200 + d];
    float cph = cosf(ph), sph = sinf(ph);
    q[(0*8 + b)*200 + d] = her*cph - hei*sph;          // p_re
    q[(1*8 + b)*200 + d] = her*sph + hei*cph;          // p_im

    float cer = ce_re[h*200+d], cei = ce_im[h*200+d];
    float crr = cr_re[r*200+d], cri = cr_im[r*200+d];
    q[(2*8 + b)*200 + d] = cer*crr - cei*cri;          // s_re
    q[(3*8 + b)*200 + d] = cer*cri + cei*crr;          // s_im

    q[(4*8 + b)*200 + d] = ke[h*200+d] * kr[r*200+d];
    q[(5*8 + b)*200 + d] = de[h*200+d] * dr[r*200+d];
    q[(6*8 + b)*200 + d] = se_h[h*200+d] * sr[r*200+d];     // pairs with se_t[e]
    q[(7*8 + b)*200 + d] = se_t[h*200+d] * sr_inv[r*200+d]; // pairs with se_h[e]
}

// ---------------- K_main v3: async LDS staging + coalesced loads ----------------
// 512 threads = 8 waves. Staging: wave w stages array w (2 x global_load_lds of 1KB).
// Compute: thread = (ds = tid>>7, r = (tid>>3)&15, b = tid&7), 8 floats per 32-chunk.
// LDS entity tile [2][8 arrays][16 e][32 d], XOR-swizzled (slot ^ (row&7)) via
// pre-swizzled GLOBAL source addresses (LDS dest stays linear for global_load_lds).
__global__ __launch_bounds__(512, 6) void k_main(
    const float* __restrict__ eemb, const float* __restrict__ ce_re,
    const float* __restrict__ ce_im, const float* __restrict__ ke,
    const float* __restrict__ de, const float* __restrict__ se_h,
    const float* __restrict__ se_t, float* __restrict__ ws)
{
    __shared__ __align__(16) float ebuf[2][8][16][32];   // 32 KB
    __shared__ float4 red2[2][40];

    const float* q = ws + Q_OFF;
    float* S    = ws + S_OFF;
    float* part = ws + PART_OFF;

    const int tid = threadIdx.x;
    const int w   = tid >> 6;        // wave id = staged array id
    const int l   = tid & 63;
    const int ds  = tid >> 7;        // d-quarter 0..3
    const int r   = (tid >> 3) & 15; // entity in tile
    const int b   = tid & 7;
    const int e0  = blockIdx.x * 16;

    // this wave's staging source
    const float* gb; int gs, go;
    switch (w) {
        case 0: gb = eemb;  gs = 400; go = 0;   break;  // t_re
        case 1: gb = eemb;  gs = 400; go = 200; break;  // t_im
        case 2: gb = ce_re; gs = 200; go = 0;   break;
        case 3: gb = ce_im; gs = 200; go = 0;   break;
        case 4: gb = ke;    gs = 200; go = 0;   break;
        case 5: gb = de;    gs = 200; go = 0;   break;
        case 6: gb = se_t;  gs = 200; go = 0;   break;  // pairs q6
        default:gb = se_h;  gs = 200; go = 0;   break;  // pairs q7
    }
    const int sl = l & 7;     // 16B slot within 128B row-chunk
    const int rl = l >> 3;    // row within 8-row group

    auto stage = [&](int buf, int c) {
#pragma unroll
        for (int i = 0; i < 2; ++i) {
            int rr  = i*8 + rl;
            int col = c*32 + ((sl ^ (rr & 7)) << 2);   // pre-swizzled global col
            if (col + 4 > 200) col = 0;                // clamp tail (content unused)
            const float* gp = gb + (size_t)(e0 + rr) * gs + go + col;
            float* lp = &ebuf[buf][w][i*8][0];         // wave-uniform base; HW adds lane*16
            __builtin_amdgcn_global_load_lds(
                (const __attribute__((address_space(1))) void*)gp,
                (__attribute__((address_space(3))) void*)lp, 16, 0, 0);
        }
    };

    float a0=0.f, a1=0.f, a2=0.f, a3=0.f, a4=0.f;

    stage(0, 0);
    for (int c = 0; c < 7; ++c) {
        __syncthreads();                       // drains vmcnt -> chunk c staged
        if (c < 6) stage((c+1)&1, c+1);        // prefetch next chunk (other buffer)
        int dbase = c*32 + ds*8;
        if (dbase < 200) {
            const float* lrow = &ebuf[c&1][0][r][0];   // + a*512 + slot*4
            const float* qb2  = q + b*200 + dbase;     // + v*1600
            const int pa = ((ds*2+0) ^ (r & 7)) << 2;  // phys slot bytes/4 for j=0
            const int pb = ((ds*2+1) ^ (r & 7)) << 2;  // j=1

            { // rotate: q0,q1 vs t_re,t_im
                float4 q0a = LD4(qb2);        float4 q0b = LD4(qb2+4);
                float4 q1a = LD4(qb2+1600);   float4 q1b = LD4(qb2+1604);
                float4 t0a = LD4(lrow+0*512+pa); float4 t0b = LD4(lrow+0*512+pb);
                float4 t1a = LD4(lrow+1*512+pa); float4 t1b = LD4(lrow+1*512+pb);
#pragma unroll
                for (int k = 0; k < 4; ++k) {
                    float dre = COMP(q0a,k)-COMP(t0a,k), dim = COMP(q1a,k)-COMP(t1a,k);
                    a0 += __builtin_amdgcn_sqrtf(fmaf(dre,dre,dim*dim));
                    dre = COMP(q0b,k)-COMP(t0b,k); dim = COMP(q1b,k)-COMP(t1b,k);
                    a0 += __builtin_amdgcn_sqrtf(fmaf(dre,dre,dim*dim));
                }
            }
            { // complex: q2·ce_re + q3·ce_im
                float4 q2a = LD4(qb2+3200);   float4 q2b = LD4(qb2+3204);
                float4 q3a = LD4(qb2+4800);   float4 q3b = LD4(qb2+4804);
                float4 c0a = LD4(lrow+2*512+pa); float4 c0b = LD4(lrow+2*512+pb);
                float4 c1a = LD4(lrow+3*512+pa); float4 c1b = LD4(lrow+3*512+pb);
#pragma unroll
                for (int k = 0; k < 4; ++k) {
                    a1 = fmaf(COMP(q2a,k), COMP(c0a,k), fmaf(COMP(q3a,k), COMP(c1a,k), a1));
                    a1 = fmaf(COMP(q2b,k), COMP(c0b,k), fmaf(COMP(q3b,k), COMP(c1b,k), a1));
                }
            }
            { // kdg + distmult
                float4 q4a = LD4(qb2+6400);   float4 q4b = LD4(qb2+6404);
                float4 k0a = LD4(lrow+4*512+pa); float4 k0b = LD4(lrow+4*512+pb);
                float4 q5a = LD4(qb2+8000);   float4 q5b = LD4(qb2+8004);
                float4 d0a = LD4(lrow+5*512+pa); float4 d0b = LD4(lrow+5*512+pb);
#pragma unroll
                for (int k = 0; k < 4; ++k) {
                    a2 = fmaf(COMP(q4a,k), COMP(k0a,k), a2);
                    a2 = fmaf(COMP(q4b,k), COMP(k0b,k), a2);
                    a3 = fmaf(COMP(q5a,k), COMP(d0a,k), a3);
                    a3 = fmaf(COMP(q5b,k), COMP(d0b,k), a3);
                }
            }
            { // simple: q6·se_t + q7·se_h
                float4 q6a = LD4(qb2+9600);   float4 q6b = LD4(qb2+9604);
                float4 q7a = LD4(qb2+11200);  float4 q7b = LD4(qb2+11204);
                float4 s0a = LD4(lrow+6*512+pa); float4 s0b = LD4(lrow+6*512+pb);
                float4 s1a = LD4(lrow+7*512+pa); float4 s1b = LD4(lrow+7*512+pb);
#pragma unroll
                for (int k = 0; k < 4; ++k) {
                    a4 = fmaf(COMP(q6a,k), COMP(s0a,k), fmaf(COMP(q7a,k), COMP(s1a,k), a4));
                    a4 = fmaf(COMP(q6b,k), COMP(s0b,k), fmaf(COMP(q7b,k), COMP(s1b,k), a4));
                }
            }
        }
    }

    // cross-wave (d-quarter) reduction: overlay scratch on ebuf
    __syncthreads();
    float* redp = &ebuf[0][0][0][0];
    {
        int idx = tid & 127;
        float vv[5] = {a0, a1, a2, a3, a4};
#pragma unroll
        for (int m = 0; m < 5; ++m) redp[(ds*128 + idx)*5 + m] = vv[m];
    }
    __syncthreads();
    if (tid < 128) {
        float vals[5];
#pragma unroll
        for (int m = 0; m < 5; ++m) {
            float s = 0.f;
#pragma unroll
            for (int d2 = 0; d2 < 4; ++d2) s += redp[(d2*128 + tid)*5 + m];
            vals[m] = s;
        }
        vals[0] = -vals[0];
        vals[4] = 0.5f * vals[4];
        int e = e0 + (tid >> 3);
#pragma unroll
        for (int m = 0; m < 5; ++m) S[(m*8 + b)*N_ENT + e] = vals[m];

        float mn[5], mx[5], sm[5], sq[5];
#pragma unroll
        for (int m = 0; m < 5; ++m) {
            mn[m] = vals[m]; mx[m] = vals[m]; sm[m] = vals[m]; sq[m] = vals[m]*vals[m];
        }
#pragma unroll
        for (int off = 8; off <= 32; off <<= 1) {
#pragma unroll
            for (int m = 0; m < 5; ++m) {
                mn[m] = fminf(mn[m], __shfl_xor(mn[m], off, 64));
                mx[m] = fmaxf(mx[m], __shfl_xor(mx[m], off, 64));
                sm[m] += __shfl_xor(sm[m], off, 64);
                sq[m] += __shfl_xor(sq[m], off, 64);
            }
        }
        if ((tid & 63) < 8) {   // lane holds b = tid&7, entities-half = tid>>6
#pragma unroll
            for (int m = 0; m < 5; ++m)
                red2[tid >> 6][m*8 + b] = make_float4(mn[m], mx[m], sm[m], sq[m]);
        }
    }
    __syncthreads();
    if (tid < 40) {
        float4 u = red2[0][tid], v = red2[1][tid];
        float4 o;
        o.x = fminf(u.x, v.x);
        o.y = fmaxf(u.y, v.y);
        o.z = u.z + v.z;
        o.w = u.w + v.w;
        *(float4*)(part + (blockIdx.x*40 + tid)*4) = o;
    }
}

// ---------------- K_red: reduce 1250 partials per (m,b) pair ----------------
__global__ __launch_bounds__(64) void k_red(float* __restrict__ ws)
{
    const float* part = ws + PART_OFF;
    int p = blockIdx.x;      // 0..39 = m*8+b
    int l = threadIdx.x;
    float mn = INFINITY, mx = -INFINITY;
    double sm = 0.0, sq = 0.0;
    for (int blk = l; blk < NBLK_MAIN; blk += 64) {
        float4 v = *(const float4*)(part + (blk*40 + p)*4);
        mn = fminf(mn, v.x); mx = fmaxf(mx, v.y);
        sm += (double)v.z;   sq += (double)v.w;
    }
#pragma unroll
    for (int off = 1; off < 64; off <<= 1) {
        mn = fminf(mn, __shfl_xor(mn, off, 64));
        mx = fmaxf(mx, __shfl_xor(mx, off, 64));
        sm += __shfl_xor(sm, off, 64);
        sq += __shfl_xor(sq, off, 64);
    }
    if (l == 0) {
        ws[MNMX_OFF + p*2]     = mn;
        ws[MNMX_OFF + p*2 + 1] = mx;
        double* sd = (double*)(ws + STATD_OFF);
        sd[p*2]     = sm;
        sd[p*2 + 1] = sq;
    }
}

// ---------------- K_mlp: features + 5-expert MLP + affine coefficients ----------------
__global__ __launch_bounds__(320) void k_mlp(
    const float* __restrict__ W0, const float* __restrict__ b0,
    const float* __restrict__ W1, const float* __restrict__ b1,
    const float* __restrict__ W2, const float* __restrict__ b2,
    const float* __restrict__ W3, const float* __restrict__ b3,
    float* __restrict__ ws)
{
    __shared__ float feat[NB][10];
    __shared__ float mnS[NM][NB], rngS[NM][NB];
    __shared__ float xA[NM][NB][64], xB[NM][NB][64];
    __shared__ float wS[NM][NB];

    int t = threadIdx.x;
    if (t < 40) {
        int m = t / 8, b = t % 8;
        float  mn = ws[MNMX_OFF + t*2];
        float  mx = ws[MNMX_OFF + t*2 + 1];
        const double* sd = (const double*)(ws + STATD_OFF);
        double sm = sd[t*2], sq = sd[t*2 + 1];
        float  rng  = mx - mn;
        double mean = sm / (double)N_ENT;
        float  md   = 1.0f - (float)((mean - (double)mn) / (double)rng);
        double va   = (sq - sm*sm/(double)N_ENT) / (double)(N_ENT - 1);
        float  vn   = (float)(va / ((double)rng * (double)rng));
        feat[b][2*m]   = md;
        feat[b][2*m+1] = vn;
        mnS[m][b] = mn; rngS[m][b] = rng;
    }
    __syncthreads();

    int ex = t / 64, o = t % 64;
    for (int b = 0; b < NB; ++b) {
        float a = b0[ex*64 + o];
#pragma unroll
        for (int i = 0; i < 10; ++i) a = fmaf(feat[b][i], W0[ex*640 + i*64 + o], a);
        xA[ex][b][o] = a;
    }
    __syncthreads();
    for (int b = 0; b < NB; ++b) {
        float a = b1[ex*64 + o];
        for (int i = 0; i < 64; ++i) a = fmaf(xA[ex][b][i], W1[ex*4096 + i*64 + o], a);
        xB[ex][b][o] = fmaxf(a, 0.f);
    }
    __syncthreads();
    for (int b = 0; b < NB; ++b) {
        float a = b2[ex*64 + o];
        for (int i = 0; i < 64; ++i) a = fmaf(xB[ex][b][i], W2[ex*4096 + i*64 + o], a);
        xA[ex][b][o] = fmaxf(a, 0.f);
    }
    __syncthreads();
    if (o == 0) {
        for (int b = 0; b < NB; ++b) {
            float a = b3[ex];
            for (int i = 0; i < 64; ++i) a = fmaf(xA[ex][b][i], W3[ex*64 + i], a);
            wS[ex][b] = fmaxf(a, 0.f);
        }
    }
    __syncthreads();
    if (t < 8) {
        int b = t;
        float wm = 0.f;
        for (int m = 0; m < NM; ++m) wm = fmaxf(wm, fabsf(wS[m][b]));
        float cst = 0.f;
        for (int m = 0; m < NM; ++m) {
            float w  = wS[m][b] / wm;
            float cc = w / rngS[m][b];
            ws[C_OFF + m*8 + b] = cc;
            cst -= cc * mnS[m][b];
        }
        ws[CONST_OFF + b] = cst;
    }
}

// ---------------- K_combine ----------------
__global__ __launch_bounds__(256) void k_comb(const float* __restrict__ ws,
                                              float* __restrict__ out)
{
    int t = blockIdx.x * 256 + threadIdx.x;
    if (t >= NB * (N_ENT/4)) return;
    int b = t / (N_ENT/4);
    int e = (t % (N_ENT/4)) * 4;
    const float* S = ws + S_OFF;
    float c0 = ws[C_OFF +  0 + b], c1 = ws[C_OFF +  8 + b], c2 = ws[C_OFF + 16 + b];
    float c3 = ws[C_OFF + 24 + b], c4 = ws[C_OFF + 32 + b];
    float cst = ws[CONST_OFF + b];
    float4 s0 = *(const float4*)(S + (0*8 + b)*N_ENT + e);
    float4 s1 = *(const float4*)(S + (1*8 + b)*N_ENT + e);
    float4 s2 = *(const float4*)(S + (2*8 + b)*N_ENT + e);
    float4 s3 = *(const float4*)(S + (3*8 + b)*N_ENT + e);
    float4 s4 = *(const float4*)(S + (4*8 + b)*N_ENT + e);
    float4 o4;
    o4.x = fmaf(c0,s0.x, fmaf(c1,s1.x, fmaf(c2,s2.x, fmaf(c3,s3.x, fmaf(c4,s4.x, cst)))));
    o4.y = fmaf(c0,s0.y, fmaf(c1,s1.y, fmaf(c2,s2.y, fmaf(c3,s3.y, fmaf(c4,s4.y, cst)))));
    o4.z = fmaf(c0,s0.z, fmaf(c1,s1.z, fmaf(c2,s2.z, fmaf(c3,s3.z, fmaf(c4,s4.z, cst)))));
    o4.w = fmaf(c0,s0.w, fmaf(c1,s1.w, fmaf(c2,s2.w, fmaf(c3,s3.w, fmaf(c4,s4.w, cst)))));
    *(float4*)(out + b*N_ENT + e) = o4;
}

extern "C" void kernel_launch(void* const* d_in, const int* in_sizes, int n_in,
                              void* d_out, int out_size, void* d_ws, size_t ws_size,
                              hipStream_t stream)
{
    const int*   batch  = (const int*)  d_in[0];
    const float* eemb   = (const float*)d_in[1];
    const float* remb   = (const float*)d_in[2];
    const float* ce_re  = (const float*)d_in[3];
    const float* ce_im  = (const float*)d_in[4];
    const float* cr_re  = (const float*)d_in[5];
    const float* cr_im  = (const float*)d_in[6];
    const float* de     = (const float*)d_in[7];
    const float* dr     = (const float*)d_in[8];
    const float* ke     = (const float*)d_in[9];
    const float* kr     = (const float*)d_in[10];
    const float* se_h   = (const float*)d_in[11];
    const float* se_t   = (const float*)d_in[12];
    const float* sr     = (const float*)d_in[13];
    const float* sr_inv = (const float*)d_in[14];
    const float* W0 = (const float*)d_in[15];
    const float* b0 = (const float*)d_in[16];
    const float* W1 = (const float*)d_in[17];
    const float* b1 = (const float*)d_in[18];
    const float* W2 = (const float*)d_in[19];
    const float* b2 = (const float*)d_in[20];
    const float* W3 = (const float*)d_in[21];
    const float* b3 = (const float*)d_in[22];
    float* ws  = (float*)d_ws;
    float* out = (float*)d_out;

    k_q    <<<8, 256, 0, stream>>>(batch, eemb, remb, ce_re, ce_im, cr_re, cr_im,
                                   de, dr, ke, kr, se_h, se_t, sr, sr_inv, ws);
    k_main <<<NBLK_MAIN, 512, 0, stream>>>(eemb, ce_re, ce_im, ke, de, se_h, se_t, ws);
    k_red  <<<40, 64, 0, stream>>>(ws);
    k_mlp  <<<1, 320, 0, stream>>>(W0, b0, W1, b1, W2, b2, W3, b3, ws);
    k_comb <<<(NB*(N_ENT/4) + 255)/256, 256, 0, stream>>>(ws, out);
}

// Round 4
// 102.568 us; speedup vs baseline: 2.4730x; 1.0595x over previous
//
#include <hip/hip_runtime.h>
#include <math.h>

#define N_ENT 20000
#define D 200
#define NB 8
#define NM 5
#define NBLK_MAIN 1250   // 16 entities per block

// ws layout (in floats)
#define Q_OFF     0        // 8 vec * 8 b * 200 = 12800
#define PART_OFF  12800    // 1250 blocks * 40 pairs * 4 = 200000
#define C_OFF     213040   // 40
#define CONST_OFF 213080   // 8
#define S_OFF     213088   // 5*8*20000 = 800000

#define COMP(v,j) ((j)==0 ? (v).x : (j)==1 ? (v).y : (j)==2 ? (v).z : (v).w)
#define LD4(p) (*(const float4*)(p))

// ---------------- K_q: build 8 per-b query vectors into ws ----------------
__global__ __launch_bounds__(256) void k_q(
    const int* __restrict__ batch, const float* __restrict__ eemb,
    const float* __restrict__ remb,
    const float* __restrict__ ce_re, const float* __restrict__ ce_im,
    const float* __restrict__ cr_re, const float* __restrict__ cr_im,
    const float* __restrict__ de, const float* __restrict__ dr,
    const float* __restrict__ ke, const float* __restrict__ kr,
    const float* __restrict__ se_h, const float* __restrict__ se_t,
    const float* __restrict__ sr, const float* __restrict__ sr_inv,
    float* __restrict__ ws)
{
    int b = blockIdx.x;
    int d = threadIdx.x;
    if (d >= D) return;
    int h = batch[b*48 + 0];
    int r = batch[b*48 + 2];
    float* q = ws + Q_OFF;

    float her = eemb[h*400 + d];
    float hei = eemb[h*400 + 200 + d];
    float ph  = remb[r*200 + d];
    float cph = cosf(ph), sph = sinf(ph);
    q[(0*8 + b)*200 + d] = her*cph - hei*sph;          // p_re
    q[(1*8 + b)*200 + d] = her*sph + hei*cph;          // p_im

    float cer = ce_re[h*200+d], cei = ce_im[h*200+d];
    float crr = cr_re[r*200+d], cri = cr_im[r*200+d];
    q[(2*8 + b)*200 + d] = cer*crr - cei*cri;          // s_re
    q[(3*8 + b)*200 + d] = cer*cri + cei*crr;          // s_im

    q[(4*8 + b)*200 + d] = ke[h*200+d] * kr[r*200+d];
    q[(5*8 + b)*200 + d] = de[h*200+d] * dr[r*200+d];
    q[(6*8 + b)*200 + d] = se_h[h*200+d] * sr[r*200+d];     // pairs with se_t[e]
    q[(7*8 + b)*200 + d] = se_t[h*200+d] * sr_inv[r*200+d]; // pairs with se_h[e]
}

// ---------------- K_main v5 ----------------
// 256 threads = 4 waves. thread = (ds = tid>>5 : d-quad, rg = (tid>>2)&7 : e-pair,
// bg = tid&3 : b-pair). Register tile 2e x 2b, acc[5][2][2].
// LDS: ebuf [2][8 arr][16 e][32 d] (32 KB) + qbuf [2][8 vec][8 b][32 d] (16 KB),
// both XOR-swizzled (slot ^ row&7) via pre-swizzled GLOBAL source columns.
// Staging: wave w stages arrays {2w,2w+1} (4 instr) + q-vecs {2w,2w+1} (2 instr).
__global__ __launch_bounds__(256, 3) void k_main(
    const float* __restrict__ eemb, const float* __restrict__ ce_re,
    const float* __restrict__ ce_im, const float* __restrict__ ke,
    const float* __restrict__ de, const float* __restrict__ se_h,
    const float* __restrict__ se_t, float* __restrict__ ws)
{
    __shared__ __align__(16) float ebuf[2][8][16][32];   // 32 KB
    __shared__ __align__(16) float qbuf[2][8][8][32];    // 16 KB
    __shared__ float4 red2[2][40];

    const float* qg = ws + Q_OFF;
    float* S    = ws + S_OFF;
    float* part = ws + PART_OFF;

    const int tid = threadIdx.x;
    const int wv  = tid >> 6;        // wave 0..3
    const int l   = tid & 63;
    const int bg  = tid & 3;         // b-pair: b = 2bg+jb
    const int rg  = (tid >> 2) & 7;  // e-pair: e = 2rg+je
    const int ds  = tid >> 5;        // d-quad 0..7 within chunk
    const int e0  = blockIdx.x * 16;

    // this wave's two staged arrays
    const float *gb0, *gb1; int gs0, go0, gs1, go1;
    switch (wv) {
        case 0: gb0 = eemb;  gs0 = 400; go0 = 0; gb1 = eemb;  gs1 = 400; go1 = 200; break;
        case 1: gb0 = ce_re; gs0 = 200; go0 = 0; gb1 = ce_im; gs1 = 200; go1 = 0;   break;
        case 2: gb0 = ke;    gs0 = 200; go0 = 0; gb1 = de;    gs1 = 200; go1 = 0;   break;
        default:gb0 = se_t;  gs0 = 200; go0 = 0; gb1 = se_h;  gs1 = 200; go1 = 0;   break;
    }
    const int sl = l & 7;     // 16B slot within 128B row-chunk
    const int rl = l >> 3;    // row within 8-row group

    auto stage = [&](int buf, int c) {
#pragma unroll
        for (int a = 0; a < 2; ++a) {
            const float* gbase = a ? gb1 : gb0;
            const int gs_ = a ? gs1 : gs0, go_ = a ? go1 : go0;
#pragma unroll
            for (int i = 0; i < 2; ++i) {
                int rr  = i*8 + rl;
                int col = c*32 + ((sl ^ (rr & 7)) << 2);
                if (col + 4 > 200) col = 0;                // tail clamp (unused content)
                const float* gp = gbase + (size_t)(e0 + rr) * gs_ + go_ + col;
                float* lp = &ebuf[buf][2*wv + a][i*8][0];
                __builtin_amdgcn_global_load_lds(
                    (const __attribute__((address_space(1))) void*)gp,
                    (__attribute__((address_space(3))) void*)lp, 16, 0, 0);
            }
        }
#pragma unroll
        for (int a = 0; a < 2; ++a) {
            int v   = 2*wv + a;
            int col = c*32 + ((sl ^ rl) << 2);             // row = b = rl
            if (col + 4 > 200) col = 0;
            const float* gp = qg + (size_t)(v*8 + rl) * 200 + col;
            float* lp = &qbuf[buf][v][0][0];
            __builtin_amdgcn_global_load_lds(
                (const __attribute__((address_space(1))) void*)gp,
                (__attribute__((address_space(3))) void*)lp, 16, 0, 0);
        }
    };

    float acc[NM][2][2];
#pragma unroll
    for (int m = 0; m < NM; ++m)
#pragma unroll
        for (int je = 0; je < 2; ++je)
#pragma unroll
            for (int jb = 0; jb < 2; ++jb) acc[m][je][jb] = 0.f;

    const int eA = 2*rg, eB = 2*rg + 1;
    const int bA = 2*bg, bB = 2*bg + 1;
    const int peA = ((ds ^ (eA & 7)) << 2), peB = ((ds ^ (eB & 7)) << 2);
    const int pqA = ((ds ^ bA) << 2),       pqB = ((ds ^ bB) << 2);

    stage(0, 0);
    for (int c = 0; c < 7; ++c) {
        __syncthreads();                       // stage(c) complete
        if (c < 6) stage((c+1)&1, c+1);        // 1-deep prefetch into other buffer
        if (c*32 + ds*4 < 200) {
            const float* eb = &ebuf[c&1][0][0][0];
            const float* qb = &qbuf[c&1][0][0][0];
#define ELOAD(arr, pe, e) LD4(eb + (((arr)*16 + (e))*32) + (pe))
#define QLOAD(v, pq, b)   LD4(qb + (((v)*8 + (b))*32) + (pq))
            { // rotate: q0 (p_re), q1 (p_im) vs t_re, t_im
                float4 q0A=QLOAD(0,pqA,bA), q0B=QLOAD(0,pqB,bB);
                float4 q1A=QLOAD(1,pqA,bA), q1B=QLOAD(1,pqB,bB);
                float4 t0A=ELOAD(0,peA,eA), t0B=ELOAD(0,peB,eB);
                float4 t1A=ELOAD(1,peA,eA), t1B=ELOAD(1,peB,eB);
#pragma unroll
                for (int k = 0; k < 4; ++k) {
                    float dr_, di_;
                    dr_=COMP(q0A,k)-COMP(t0A,k); di_=COMP(q1A,k)-COMP(t1A,k);
                    acc[0][0][0] += __builtin_amdgcn_sqrtf(fmaf(dr_,dr_,di_*di_));
                    dr_=COMP(q0B,k)-COMP(t0A,k); di_=COMP(q1B,k)-COMP(t1A,k);
                    acc[0][0][1] += __builtin_amdgcn_sqrtf(fmaf(dr_,dr_,di_*di_));
                    dr_=COMP(q0A,k)-COMP(t0B,k); di_=COMP(q1A,k)-COMP(t1B,k);
                    acc[0][1][0] += __builtin_amdgcn_sqrtf(fmaf(dr_,dr_,di_*di_));
                    dr_=COMP(q0B,k)-COMP(t0B,k); di_=COMP(q1B,k)-COMP(t1B,k);
                    acc[0][1][1] += __builtin_amdgcn_sqrtf(fmaf(dr_,dr_,di_*di_));
                }
            }
            { // complex: q2·ce_re + q3·ce_im
                float4 q2A=QLOAD(2,pqA,bA), q2B=QLOAD(2,pqB,bB);
                float4 q3A=QLOAD(3,pqA,bA), q3B=QLOAD(3,pqB,bB);
                float4 c0A=ELOAD(2,peA,eA), c0B=ELOAD(2,peB,eB);
                float4 c1A=ELOAD(3,peA,eA), c1B=ELOAD(3,peB,eB);
#pragma unroll
                for (int k = 0; k < 4; ++k) {
                    acc[1][0][0]=fmaf(COMP(q2A,k),COMP(c0A,k),fmaf(COMP(q3A,k),COMP(c1A,k),acc[1][0][0]));
                    acc[1][0][1]=fmaf(COMP(q2B,k),COMP(c0A,k),fmaf(COMP(q3B,k),COMP(c1A,k),acc[1][0][1]));
                    acc[1][1][0]=fmaf(COMP(q2A,k),COMP(c0B,k),fmaf(COMP(q3A,k),COMP(c1B,k),acc[1][1][0]));
                    acc[1][1][1]=fmaf(COMP(q2B,k),COMP(c0B,k),fmaf(COMP(q3B,k),COMP(c1B,k),acc[1][1][1]));
                }
            }
            { // kdg + distmult
                float4 q4A=QLOAD(4,pqA,bA), q4B=QLOAD(4,pqB,bB);
                float4 k0A=ELOAD(4,peA,eA), k0B=ELOAD(4,peB,eB);
                float4 q5A=QLOAD(5,pqA,bA), q5B=QLOAD(5,pqB,bB);
                float4 d0A=ELOAD(5,peA,eA), d0B=ELOAD(5,peB,eB);
#pragma unroll
                for (int k = 0; k < 4; ++k) {
                    acc[2][0][0]=fmaf(COMP(q4A,k),COMP(k0A,k),acc[2][0][0]);
                    acc[2][0][1]=fmaf(COMP(q4B,k),COMP(k0A,k),acc[2][0][1]);
                    acc[2][1][0]=fmaf(COMP(q4A,k),COMP(k0B,k),acc[2][1][0]);
                    acc[2][1][1]=fmaf(COMP(q4B,k),COMP(k0B,k),acc[2][1][1]);
                    acc[3][0][0]=fmaf(COMP(q5A,k),COMP(d0A,k),acc[3][0][0]);
                    acc[3][0][1]=fmaf(COMP(q5B,k),COMP(d0A,k),acc[3][0][1]);
                    acc[3][1][0]=fmaf(COMP(q5A,k),COMP(d0B,k),acc[3][1][0]);
                    acc[3][1][1]=fmaf(COMP(q5B,k),COMP(d0B,k),acc[3][1][1]);
                }
            }
            { // simple: q6·se_t + q7·se_h
                float4 q6A=QLOAD(6,pqA,bA), q6B=QLOAD(6,pqB,bB);
                float4 q7A=QLOAD(7,pqA,bA), q7B=QLOAD(7,pqB,bB);
                float4 s0A=ELOAD(6,peA,eA), s0B=ELOAD(6,peB,eB);
                float4 s1A=ELOAD(7,peA,eA), s1B=ELOAD(7,peB,eB);
#pragma unroll
                for (int k = 0; k < 4; ++k) {
                    acc[4][0][0]=fmaf(COMP(q6A,k),COMP(s0A,k),fmaf(COMP(q7A,k),COMP(s1A,k),acc[4][0][0]));
                    acc[4][0][1]=fmaf(COMP(q6B,k),COMP(s0A,k),fmaf(COMP(q7B,k),COMP(s1A,k),acc[4][0][1]));
                    acc[4][1][0]=fmaf(COMP(q6A,k),COMP(s0B,k),fmaf(COMP(q7A,k),COMP(s1B,k),acc[4][1][0]));
                    acc[4][1][1]=fmaf(COMP(q6B,k),COMP(s0B,k),fmaf(COMP(q7B,k),COMP(s1B,k),acc[4][1][1]));
                }
            }
        }
    }

    // ---- cross-ds reduction via LDS overlay on ebuf ----
    __syncthreads();
    float* ov = &ebuf[0][0][0][0];   // 256 threads * 20 floats = 5120 < 8192
    {
        int base = tid * 20;
#pragma unroll
        for (int m = 0; m < NM; ++m)
#pragma unroll
            for (int je = 0; je < 2; ++je)
#pragma unroll
                for (int jb = 0; jb < 2; ++jb)
                    ov[base + m*4 + je*2 + jb] = acc[m][je][jb];
    }
    __syncthreads();
    if (tid < 128) {
        int e_l = tid >> 3, b = tid & 7;
        int rg2 = e_l >> 1, je = e_l & 1, bg2 = b >> 1, jb = b & 1;
        float vals[NM];
#pragma unroll
        for (int m = 0; m < NM; ++m) {
            float s = 0.f;
#pragma unroll
            for (int d2 = 0; d2 < 8; ++d2)
                s += ov[((d2 << 5) | (rg2 << 2) | bg2) * 20 + m*4 + je*2 + jb];
            vals[m] = s;
        }
        vals[0] = -vals[0];
        vals[4] = 0.5f * vals[4];
        int e = e0 + e_l;
#pragma unroll
        for (int m = 0; m < NM; ++m) S[(m*8 + b)*N_ENT + e] = vals[m];

        float mn[NM], mx[NM], sm[NM], sq[NM];
#pragma unroll
        for (int m = 0; m < NM; ++m) {
            mn[m] = vals[m]; mx[m] = vals[m]; sm[m] = vals[m]; sq[m] = vals[m]*vals[m];
        }
#pragma unroll
        for (int off = 8; off <= 32; off <<= 1) {
#pragma unroll
            for (int m = 0; m < NM; ++m) {
                mn[m] = fminf(mn[m], __shfl_xor(mn[m], off, 64));
                mx[m] = fmaxf(mx[m], __shfl_xor(mx[m], off, 64));
                sm[m] += __shfl_xor(sm[m], off, 64);
                sq[m] += __shfl_xor(sq[m], off, 64);
            }
        }
        if ((tid & 63) < 8) {   // lane b = tid&7, e-half = tid>>6
#pragma unroll
            for (int m = 0; m < NM; ++m)
                red2[tid >> 6][m*8 + b] = make_float4(mn[m], mx[m], sm[m], sq[m]);
        }
    }
    __syncthreads();
    if (tid < 40) {
        float4 u = red2[0][tid], v = red2[1][tid];
        float4 o;
        o.x = fminf(u.x, v.x);
        o.y = fmaxf(u.y, v.y);
        o.z = u.z + v.z;
        o.w = u.w + v.w;
        *(float4*)(part + (blockIdx.x*40 + tid)*4) = o;
    }
}

// ---------------- K_mlp: 1250-partial reduction + features + MLP + coefficients ----------------
__global__ __launch_bounds__(320) void k_mlp(
    const float* __restrict__ W0, const float* __restrict__ b0,
    const float* __restrict__ W1, const float* __restrict__ b1,
    const float* __restrict__ W2, const float* __restrict__ b2,
    const float* __restrict__ W3, const float* __restrict__ b3,
    float* __restrict__ ws)
{
    const float* part = ws + PART_OFF;
    __shared__ float  redmn[8][40], redmx[8][40];
    __shared__ double redsm[8][40], redsq[8][40];
    __shared__ float  feat[NB][10];
    __shared__ float  mnS[NM][NB], rngS[NM][NB];
    __shared__ float  xA[NM][NB][64], xB[NM][NB][64];
    __shared__ float  wS[NM][NB];

    int t = threadIdx.x;
    {   // sliced reduction over 1250 block-partials
        int p = t % 40, sl = t / 40;  // sl in [0,8)
        float mn = INFINITY, mx = -INFINITY; double sm = 0.0, sq = 0.0;
        for (int blk = sl; blk < NBLK_MAIN; blk += 8) {
            float4 v = *(const float4*)(part + (blk*40 + p)*4);
            mn = fminf(mn, v.x); mx = fmaxf(mx, v.y);
            sm += (double)v.z;   sq += (double)v.w;
        }
        redmn[sl][p] = mn; redmx[sl][p] = mx; redsm[sl][p] = sm; redsq[sl][p] = sq;
    }
    __syncthreads();
    if (t < 40) {
        float mn = INFINITY, mx = -INFINITY; double sm = 0.0, sq = 0.0;
        for (int sl = 0; sl < 8; ++sl) {
            mn = fminf(mn, redmn[sl][t]); mx = fmaxf(mx, redmx[sl][t]);
            sm += redsm[sl][t];           sq += redsq[sl][t];
        }
        int m = t / 8, b = t % 8;
        float  rng  = mx - mn;
        double mean = sm / (double)N_ENT;
        float  md   = 1.0f - (float)((mean - (double)mn) / (double)rng);
        double va   = (sq - sm*sm/(double)N_ENT) / (double)(N_ENT - 1);
        float  vn   = (float)(va / ((double)rng * (double)rng));
        feat[b][2*m]   = md;
        feat[b][2*m+1] = vn;
        mnS[m][b] = mn; rngS[m][b] = rng;
    }
    __syncthreads();

    int ex = t / 64, o = t % 64;
    for (int b = 0; b < NB; ++b) {
        float a = b0[ex*64 + o];
#pragma unroll
        for (int i = 0; i < 10; ++i) a = fmaf(feat[b][i], W0[ex*640 + i*64 + o], a);
        xA[ex][b][o] = a;
    }
    __syncthreads();
    for (int b = 0; b < NB; ++b) {
        float a = b1[ex*64 + o];
        for (int i = 0; i < 64; ++i) a = fmaf(xA[ex][b][i], W1[ex*4096 + i*64 + o], a);
        xB[ex][b][o] = fmaxf(a, 0.f);
    }
    __syncthreads();
    for (int b = 0; b < NB; ++b) {
        float a = b2[ex*64 + o];
        for (int i = 0; i < 64; ++i) a = fmaf(xB[ex][b][i], W2[ex*4096 + i*64 + o], a);
        xA[ex][b][o] = fmaxf(a, 0.f);
    }
    __syncthreads();
    if (o == 0) {
        for (int b = 0; b < NB; ++b) {
            float a = b3[ex];
            for (int i = 0; i < 64; ++i) a = fmaf(xA[ex][b][i], W3[ex*64 + i], a);
            wS[ex][b] = fmaxf(a, 0.f);
        }
    }
    __syncthreads();
    if (t < 8) {
        int b = t;
        float wm = 0.f;
        for (int m = 0; m < NM; ++m) wm = fmaxf(wm, fabsf(wS[m][b]));
        float cst = 0.f;
        for (int m = 0; m < NM; ++m) {
            float w  = wS[m][b] / wm;
            float cc = w / rngS[m][b];
            ws[C_OFF + m*8 + b] = cc;
            cst -= cc * mnS[m][b];
        }
        ws[CONST_OFF + b] = cst;
    }
}

// ---------------- K_combine ----------------
__global__ __launch_bounds__(256) void k_comb(const float* __restrict__ ws,
                                              float* __restrict__ out)
{
    int t = blockIdx.x * 256 + threadIdx.x;
    if (t >= NB * (N_ENT/4)) return;
    int b = t / (N_ENT/4);
    int e = (t % (N_ENT/4)) * 4;
    const float* S = ws + S_OFF;
    float c0 = ws[C_OFF +  0 + b], c1 = ws[C_OFF +  8 + b], c2 = ws[C_OFF + 16 + b];
    float c3 = ws[C_OFF + 24 + b], c4 = ws[C_OFF + 32 + b];
    float cst = ws[CONST_OFF + b];
    float4 s0 = *(const float4*)(S + (0*8 + b)*N_ENT + e);
    float4 s1 = *(const float4*)(S + (1*8 + b)*N_ENT + e);
    float4 s2 = *(const float4*)(S + (2*8 + b)*N_ENT + e);
    float4 s3 = *(const float4*)(S + (3*8 + b)*N_ENT + e);
    float4 s4 = *(const float4*)(S + (4*8 + b)*N_ENT + e);
    float4 o4;
    o4.x = fmaf(c0,s0.x, fmaf(c1,s1.x, fmaf(c2,s2.x, fmaf(c3,s3.x, fmaf(c4,s4.x, cst)))));
    o4.y = fmaf(c0,s0.y, fmaf(c1,s1.y, fmaf(c2,s2.y, fmaf(c3,s3.y, fmaf(c4,s4.y, cst)))));
    o4.z = fmaf(c0,s0.z, fmaf(c1,s1.z, fmaf(c2,s2.z, fmaf(c3,s3.z, fmaf(c4,s4.z, cst)))));
    o4.w = fmaf(c0,s0.w, fmaf(c1,s1.w, fmaf(c2,s2.w, fmaf(c3,s3.w, fmaf(c4,s4.w, cst)))));
    *(float4*)(out + b*N_ENT + e) = o4;
}

extern "C" void kernel_launch(void* const* d_in, const int* in_sizes, int n_in,
                              void* d_out, int out_size, void* d_ws, size_t ws_size,
                              hipStream_t stream)
{
    const int*   batch  = (const int*)  d_in[0];
    const float* eemb   = (const float*)d_in[1];
    const float* remb   = (const float*)d_in[2];
    const float* ce_re  = (const float*)d_in[3];
    const float* ce_im  = (const float*)d_in[4];
    const float* cr_re  = (const float*)d_in[5];
    const float* cr_im  = (const float*)d_in[6];
    const float* de     = (const float*)d_in[7];
    const float* dr     = (const float*)d_in[8];
    const float* ke     = (const float*)d_in[9];
    const float* kr     = (const float*)d_in[10];
    const float* se_h   = (const float*)d_in[11];
    const float* se_t   = (const float*)d_in[12];
    const float* sr     = (const float*)d_in[13];
    const float* sr_inv = (const float*)d_in[14];
    const float* W0 = (const float*)d_in[15];
    const float* b0 = (const float*)d_in[16];
    const float* W1 = (const float*)d_in[17];
    const float* b1 = (const float*)d_in[18];
    const float* W2 = (const float*)d_in[19];
    const float* b2 = (const float*)d_in[20];
    const float* W3 = (const float*)d_in[21];
    const float* b3 = (const float*)d_in[22];
    float* ws  = (float*)d_ws;
    float* out = (float*)d_out;

    k_q    <<<8, 256, 0, stream>>>(batch, eemb, remb, ce_re, ce_im, cr_re, cr_im,
                                   de, dr, ke, kr, se_h, se_t, sr, sr_inv, ws);
    k_main <<<NBLK_MAIN, 256, 0, stream>>>(eemb, ce_re, ce_im, ke, de, se_h, se_t, ws);
    k_mlp  <<<1, 320, 0, stream>>>(W0, b0, W1, b1, W2, b2, W3, b3, ws);
    k_comb <<<(NB*(N_ENT/4) + 255)/256, 256, 0, stream>>>(ws, out);
}

// Round 5
// 63.393 us; speedup vs baseline: 4.0013x; 1.6180x over previous
//
#include <hip/hip_runtime.h>
#include <math.h>

#define N_ENT 20000
#define D 200
#define NB 8
#define NM 5
#define NBLK_MAIN 1250   // 16 entities per block

// ws layout (in floats)
#define Q_OFF     0        // 8 vec * 8 b * 200 = 12800
#define PART_OFF  12800    // 1250 blocks * 40 pairs * 4 = 200000
#define MNMX_OFF  212800   // 40 * 2 floats
#define STATD_OFF 212880   // 40 * 2 doubles = 160 floats
#define C_OFF     213040   // 40
#define CONST_OFF 213080   // 8
#define S_OFF     213088   // 5*8*20000 = 800000

#define COMP(v,j) ((j)==0 ? (v).x : (j)==1 ? (v).y : (j)==2 ? (v).z : (v).w)
#define LD4(p) (*(const float4*)(p))

// ---------------- K_q: build 8 per-b query vectors into ws ----------------
__global__ __launch_bounds__(256) void k_q(
    const int* __restrict__ batch, const float* __restrict__ eemb,
    const float* __restrict__ remb,
    const float* __restrict__ ce_re, const float* __restrict__ ce_im,
    const float* __restrict__ cr_re, const float* __restrict__ cr_im,
    const float* __restrict__ de, const float* __restrict__ dr,
    const float* __restrict__ ke, const float* __restrict__ kr,
    const float* __restrict__ se_h, const float* __restrict__ se_t,
    const float* __restrict__ sr, const float* __restrict__ sr_inv,
    float* __restrict__ ws)
{
    int b = blockIdx.x;
    int d = threadIdx.x;
    if (d >= D) return;
    int h = batch[b*48 + 0];
    int r = batch[b*48 + 2];
    float* q = ws + Q_OFF;

    float her = eemb[h*400 + d];
    float hei = eemb[h*400 + 200 + d];
    float ph  = remb[r*200 + d];
    float cph = cosf(ph), sph = sinf(ph);
    q[(0*8 + b)*200 + d] = her*cph - hei*sph;          // p_re
    q[(1*8 + b)*200 + d] = her*sph + hei*cph;          // p_im

    float cer = ce_re[h*200+d], cei = ce_im[h*200+d];
    float crr = cr_re[r*200+d], cri = cr_im[r*200+d];
    q[(2*8 + b)*200 + d] = cer*crr - cei*cri;          // s_re
    q[(3*8 + b)*200 + d] = cer*cri + cei*crr;          // s_im

    q[(4*8 + b)*200 + d] = ke[h*200+d] * kr[r*200+d];
    q[(5*8 + b)*200 + d] = de[h*200+d] * dr[r*200+d];
    q[(6*8 + b)*200 + d] = se_h[h*200+d] * sr[r*200+d];     // pairs with se_t[e]
    q[(7*8 + b)*200 + d] = se_t[h*200+d] * sr_inv[r*200+d]; // pairs with se_h[e]
}

// ---------------- K_main v5 (unchanged from round 4) ----------------
__global__ __launch_bounds__(256, 3) void k_main(
    const float* __restrict__ eemb, const float* __restrict__ ce_re,
    const float* __restrict__ ce_im, const float* __restrict__ ke,
    const float* __restrict__ de, const float* __restrict__ se_h,
    const float* __restrict__ se_t, float* __restrict__ ws)
{
    __shared__ __align__(16) float ebuf[2][8][16][32];   // 32 KB
    __shared__ __align__(16) float qbuf[2][8][8][32];    // 16 KB
    __shared__ float4 red2[2][40];

    const float* qg = ws + Q_OFF;
    float* S    = ws + S_OFF;
    float* part = ws + PART_OFF;

    const int tid = threadIdx.x;
    const int wv  = tid >> 6;        // wave 0..3
    const int l   = tid & 63;
    const int bg  = tid & 3;         // b-pair: b = 2bg+jb
    const int rg  = (tid >> 2) & 7;  // e-pair: e = 2rg+je
    const int ds  = tid >> 5;        // d-quad 0..7 within chunk
    const int e0  = blockIdx.x * 16;

    const float *gb0, *gb1; int gs0, go0, gs1, go1;
    switch (wv) {
        case 0: gb0 = eemb;  gs0 = 400; go0 = 0; gb1 = eemb;  gs1 = 400; go1 = 200; break;
        case 1: gb0 = ce_re; gs0 = 200; go0 = 0; gb1 = ce_im; gs1 = 200; go1 = 0;   break;
        case 2: gb0 = ke;    gs0 = 200; go0 = 0; gb1 = de;    gs1 = 200; go1 = 0;   break;
        default:gb0 = se_t;  gs0 = 200; go0 = 0; gb1 = se_h;  gs1 = 200; go1 = 0;   break;
    }
    const int sl = l & 7;     // 16B slot within 128B row-chunk
    const int rl = l >> 3;    // row within 8-row group

    auto stage = [&](int buf, int c) {
#pragma unroll
        for (int a = 0; a < 2; ++a) {
            const float* gbase = a ? gb1 : gb0;
            const int gs_ = a ? gs1 : gs0, go_ = a ? go1 : go0;
#pragma unroll
            for (int i = 0; i < 2; ++i) {
                int rr  = i*8 + rl;
                int col = c*32 + ((sl ^ (rr & 7)) << 2);
                if (col + 4 > 200) col = 0;                // tail clamp (unused content)
                const float* gp = gbase + (size_t)(e0 + rr) * gs_ + go_ + col;
                float* lp = &ebuf[buf][2*wv + a][i*8][0];
                __builtin_amdgcn_global_load_lds(
                    (const __attribute__((address_space(1))) void*)gp,
                    (__attribute__((address_space(3))) void*)lp, 16, 0, 0);
            }
        }
#pragma unroll
        for (int a = 0; a < 2; ++a) {
            int v   = 2*wv + a;
            int col = c*32 + ((sl ^ rl) << 2);             // row = b = rl
            if (col + 4 > 200) col = 0;
            const float* gp = qg + (size_t)(v*8 + rl) * 200 + col;
            float* lp = &qbuf[buf][v][0][0];
            __builtin_amdgcn_global_load_lds(
                (const __attribute__((address_space(1))) void*)gp,
                (__attribute__((address_space(3))) void*)lp, 16, 0, 0);
        }
    };

    float acc[NM][2][2];
#pragma unroll
    for (int m = 0; m < NM; ++m)
#pragma unroll
        for (int je = 0; je < 2; ++je)
#pragma unroll
            for (int jb = 0; jb < 2; ++jb) acc[m][je][jb] = 0.f;

    const int eA = 2*rg, eB = 2*rg + 1;
    const int bA = 2*bg, bB = 2*bg + 1;
    const int peA = ((ds ^ (eA & 7)) << 2), peB = ((ds ^ (eB & 7)) << 2);
    const int pqA = ((ds ^ bA) << 2),       pqB = ((ds ^ bB) << 2);

    stage(0, 0);
    for (int c = 0; c < 7; ++c) {
        __syncthreads();                       // stage(c) complete
        if (c < 6) stage((c+1)&1, c+1);        // 1-deep prefetch into other buffer
        if (c*32 + ds*4 < 200) {
            const float* eb = &ebuf[c&1][0][0][0];
            const float* qb = &qbuf[c&1][0][0][0];
#define ELOAD(arr, pe, e) LD4(eb + (((arr)*16 + (e))*32) + (pe))
#define QLOAD(v, pq, b)   LD4(qb + (((v)*8 + (b))*32) + (pq))
            { // rotate
                float4 q0A=QLOAD(0,pqA,bA), q0B=QLOAD(0,pqB,bB);
                float4 q1A=QLOAD(1,pqA,bA), q1B=QLOAD(1,pqB,bB);
                float4 t0A=ELOAD(0,peA,eA), t0B=ELOAD(0,peB,eB);
                float4 t1A=ELOAD(1,peA,eA), t1B=ELOAD(1,peB,eB);
#pragma unroll
                for (int k = 0; k < 4; ++k) {
                    float dr_, di_;
                    dr_=COMP(q0A,k)-COMP(t0A,k); di_=COMP(q1A,k)-COMP(t1A,k);
                    acc[0][0][0] += __builtin_amdgcn_sqrtf(fmaf(dr_,dr_,di_*di_));
                    dr_=COMP(q0B,k)-COMP(t0A,k); di_=COMP(q1B,k)-COMP(t1A,k);
                    acc[0][0][1] += __builtin_amdgcn_sqrtf(fmaf(dr_,dr_,di_*di_));
                    dr_=COMP(q0A,k)-COMP(t0B,k); di_=COMP(q1A,k)-COMP(t1B,k);
                    acc[0][1][0] += __builtin_amdgcn_sqrtf(fmaf(dr_,dr_,di_*di_));
                    dr_=COMP(q0B,k)-COMP(t0B,k); di_=COMP(q1B,k)-COMP(t1B,k);
                    acc[0][1][1] += __builtin_amdgcn_sqrtf(fmaf(dr_,dr_,di_*di_));
                }
            }
            { // complex
                float4 q2A=QLOAD(2,pqA,bA), q2B=QLOAD(2,pqB,bB);
                float4 q3A=QLOAD(3,pqA,bA), q3B=QLOAD(3,pqB,bB);
                float4 c0A=ELOAD(2,peA,eA), c0B=ELOAD(2,peB,eB);
                float4 c1A=ELOAD(3,peA,eA), c1B=ELOAD(3,peB,eB);
#pragma unroll
                for (int k = 0; k < 4; ++k) {
                    acc[1][0][0]=fmaf(COMP(q2A,k),COMP(c0A,k),fmaf(COMP(q3A,k),COMP(c1A,k),acc[1][0][0]));
                    acc[1][0][1]=fmaf(COMP(q2B,k),COMP(c0A,k),fmaf(COMP(q3B,k),COMP(c1A,k),acc[1][0][1]));
                    acc[1][1][0]=fmaf(COMP(q2A,k),COMP(c0B,k),fmaf(COMP(q3A,k),COMP(c1B,k),acc[1][1][0]));
                    acc[1][1][1]=fmaf(COMP(q2B,k),COMP(c0B,k),fmaf(COMP(q3B,k),COMP(c1B,k),acc[1][1][1]));
                }
            }
            { // kdg + distmult
                float4 q4A=QLOAD(4,pqA,bA), q4B=QLOAD(4,pqB,bB);
                float4 k0A=ELOAD(4,peA,eA), k0B=ELOAD(4,peB,eB);
                float4 q5A=QLOAD(5,pqA,bA), q5B=QLOAD(5,pqB,bB);
                float4 d0A=ELOAD(5,peA,eA), d0B=ELOAD(5,peB,eB);
#pragma unroll
                for (int k = 0; k < 4; ++k) {
                    acc[2][0][0]=fmaf(COMP(q4A,k),COMP(k0A,k),acc[2][0][0]);
                    acc[2][0][1]=fmaf(COMP(q4B,k),COMP(k0A,k),acc[2][0][1]);
                    acc[2][1][0]=fmaf(COMP(q4A,k),COMP(k0B,k),acc[2][1][0]);
                    acc[2][1][1]=fmaf(COMP(q4B,k),COMP(k0B,k),acc[2][1][1]);
                    acc[3][0][0]=fmaf(COMP(q5A,k),COMP(d0A,k),acc[3][0][0]);
                    acc[3][0][1]=fmaf(COMP(q5B,k),COMP(d0A,k),acc[3][0][1]);
                    acc[3][1][0]=fmaf(COMP(q5A,k),COMP(d0B,k),acc[3][1][0]);
                    acc[3][1][1]=fmaf(COMP(q5B,k),COMP(d0B,k),acc[3][1][1]);
                }
            }
            { // simple
                float4 q6A=QLOAD(6,pqA,bA), q6B=QLOAD(6,pqB,bB);
                float4 q7A=QLOAD(7,pqA,bA), q7B=QLOAD(7,pqB,bB);
                float4 s0A=ELOAD(6,peA,eA), s0B=ELOAD(6,peB,eB);
                float4 s1A=ELOAD(7,peA,eA), s1B=ELOAD(7,peB,eB);
#pragma unroll
                for (int k = 0; k < 4; ++k) {
                    acc[4][0][0]=fmaf(COMP(q6A,k),COMP(s0A,k),fmaf(COMP(q7A,k),COMP(s1A,k),acc[4][0][0]));
                    acc[4][0][1]=fmaf(COMP(q6B,k),COMP(s0A,k),fmaf(COMP(q7B,k),COMP(s1A,k),acc[4][0][1]));
                    acc[4][1][0]=fmaf(COMP(q6A,k),COMP(s0B,k),fmaf(COMP(q7A,k),COMP(s1B,k),acc[4][1][0]));
                    acc[4][1][1]=fmaf(COMP(q6B,k),COMP(s0B,k),fmaf(COMP(q7B,k),COMP(s1B,k),acc[4][1][1]));
                }
            }
        }
    }

    // ---- cross-ds reduction via LDS overlay on ebuf ----
    __syncthreads();
    float* ov = &ebuf[0][0][0][0];
    {
        int base = tid * 20;
#pragma unroll
        for (int m = 0; m < NM; ++m)
#pragma unroll
            for (int je = 0; je < 2; ++je)
#pragma unroll
                for (int jb = 0; jb < 2; ++jb)
                    ov[base + m*4 + je*2 + jb] = acc[m][je][jb];
    }
    __syncthreads();
    if (tid < 128) {
        int e_l = tid >> 3, b = tid & 7;
        int rg2 = e_l >> 1, je = e_l & 1, bg2 = b >> 1, jb = b & 1;
        float vals[NM];
#pragma unroll
        for (int m = 0; m < NM; ++m) {
            float s = 0.f;
#pragma unroll
            for (int d2 = 0; d2 < 8; ++d2)
                s += ov[((d2 << 5) | (rg2 << 2) | bg2) * 20 + m*4 + je*2 + jb];
            vals[m] = s;
        }
        vals[0] = -vals[0];
        vals[4] = 0.5f * vals[4];
        int e = e0 + e_l;
#pragma unroll
        for (int m = 0; m < NM; ++m) S[(m*8 + b)*N_ENT + e] = vals[m];

        float mn[NM], mx[NM], sm[NM], sq[NM];
#pragma unroll
        for (int m = 0; m < NM; ++m) {
            mn[m] = vals[m]; mx[m] = vals[m]; sm[m] = vals[m]; sq[m] = vals[m]*vals[m];
        }
#pragma unroll
        for (int off = 8; off <= 32; off <<= 1) {
#pragma unroll
            for (int m = 0; m < NM; ++m) {
                mn[m] = fminf(mn[m], __shfl_xor(mn[m], off, 64));
                mx[m] = fmaxf(mx[m], __shfl_xor(mx[m], off, 64));
                sm[m] += __shfl_xor(sm[m], off, 64);
                sq[m] += __shfl_xor(sq[m], off, 64);
            }
        }
        if ((tid & 63) < 8) {
#pragma unroll
            for (int m = 0; m < NM; ++m)
                red2[tid >> 6][m*8 + b] = make_float4(mn[m], mx[m], sm[m], sq[m]);
        }
    }
    __syncthreads();
    if (tid < 40) {
        float4 u = red2[0][tid], v = red2[1][tid];
        float4 o;
        o.x = fminf(u.x, v.x);
        o.y = fmaxf(u.y, v.y);
        o.z = u.z + v.z;
        o.w = u.w + v.w;
        *(float4*)(part + (blockIdx.x*40 + tid)*4) = o;
    }
}

// ---------------- K_red: parallel reduction of 1250 partials per (m,b) ----------------
// 40 blocks (one per pair) x 256 threads; ~5 strided loads/thread.
__global__ __launch_bounds__(256) void k_red(float* __restrict__ ws)
{
    const float* part = ws + PART_OFF;
    const int p = blockIdx.x;      // 0..39 = m*8+b
    const int t = threadIdx.x;
    __shared__ float  smn[4], smx[4];
    __shared__ double ssm[4], ssq[4];

    float mn = INFINITY, mx = -INFINITY;
    double sm = 0.0, sq = 0.0;
    for (int blk = t; blk < NBLK_MAIN; blk += 256) {
        float4 v = LD4(part + (blk*40 + p)*4);
        mn = fminf(mn, v.x); mx = fmaxf(mx, v.y);
        sm += (double)v.z;   sq += (double)v.w;
    }
#pragma unroll
    for (int off = 1; off < 64; off <<= 1) {
        mn = fminf(mn, __shfl_xor(mn, off, 64));
        mx = fmaxf(mx, __shfl_xor(mx, off, 64));
        sm += __shfl_xor(sm, off, 64);
        sq += __shfl_xor(sq, off, 64);
    }
    if ((t & 63) == 0) {
        smn[t >> 6] = mn; smx[t >> 6] = mx; ssm[t >> 6] = sm; ssq[t >> 6] = sq;
    }
    __syncthreads();
    if (t == 0) {
        mn = fminf(fminf(smn[0], smn[1]), fminf(smn[2], smn[3]));
        mx = fmaxf(fmaxf(smx[0], smx[1]), fmaxf(smx[2], smx[3]));
        sm = ssm[0] + ssm[1] + ssm[2] + ssm[3];
        sq = ssq[0] + ssq[1] + ssq[2] + ssq[3];
        ws[MNMX_OFF + p*2]     = mn;
        ws[MNMX_OFF + p*2 + 1] = mx;
        double* sd = (double*)(ws + STATD_OFF);
        sd[p*2]     = sm;
        sd[p*2 + 1] = sq;
    }
}

// ---------------- K_mlp: features + 5-expert MLP + affine coefficients ----------------
__global__ __launch_bounds__(320) void k_mlp(
    const float* __restrict__ W0, const float* __restrict__ b0,
    const float* __restrict__ W1, const float* __restrict__ b1,
    const float* __restrict__ W2, const float* __restrict__ b2,
    const float* __restrict__ W3, const float* __restrict__ b3,
    float* __restrict__ ws)
{
    __shared__ float feat[NB][10];
    __shared__ float mnS[NM][NB], rngS[NM][NB];
    __shared__ float xA[NM][NB][64], xB[NM][NB][64];
    __shared__ float wS[NM][NB];

    int t = threadIdx.x;
    if (t < 40) {
        int m = t / 8, b = t % 8;
        float  mn = ws[MNMX_OFF + t*2];
        float  mx = ws[MNMX_OFF + t*2 + 1];
        const double* sd = (const double*)(ws + STATD_OFF);
        double sm = sd[t*2], sq = sd[t*2 + 1];
        float  rng  = mx - mn;
        double mean = sm / (double)N_ENT;
        float  md   = 1.0f - (float)((mean - (double)mn) / (double)rng);
        double va   = (sq - sm*sm/(double)N_ENT) / (double)(N_ENT - 1);
        float  vn   = (float)(va / ((double)rng * (double)rng));
        feat[b][2*m]   = md;
        feat[b][2*m+1] = vn;
        mnS[m][b] = mn; rngS[m][b] = rng;
    }
    __syncthreads();

    int ex = t / 64, o = t % 64;
    for (int b = 0; b < NB; ++b) {
        float a = b0[ex*64 + o];
#pragma unroll
        for (int i = 0; i < 10; ++i) a = fmaf(feat[b][i], W0[ex*640 + i*64 + o], a);
        xA[ex][b][o] = a;
    }
    __syncthreads();
    for (int b = 0; b < NB; ++b) {
        float a = b1[ex*64 + o];
        for (int i = 0; i < 64; ++i) a = fmaf(xA[ex][b][i], W1[ex*4096 + i*64 + o], a);
        xB[ex][b][o] = fmaxf(a, 0.f);
    }
    __syncthreads();
    for (int b = 0; b < NB; ++b) {
        float a = b2[ex*64 + o];
        for (int i = 0; i < 64; ++i) a = fmaf(xB[ex][b][i], W2[ex*4096 + i*64 + o], a);
        xA[ex][b][o] = fmaxf(a, 0.f);
    }
    __syncthreads();
    if (o == 0) {
        for (int b = 0; b < NB; ++b) {
            float a = b3[ex];
            for (int i = 0; i < 64; ++i) a = fmaf(xA[ex][b][i], W3[ex*64 + i], a);
            wS[ex][b] = fmaxf(a, 0.f);
        }
    }
    __syncthreads();
    if (t < 8) {
        int b = t;
        float wm = 0.f;
        for (int m = 0; m < NM; ++m) wm = fmaxf(wm, fabsf(wS[m][b]));
        float cst = 0.f;
        for (int m = 0; m < NM; ++m) {
            float w  = wS[m][b] / wm;
            float cc = w / rngS[m][b];
            ws[C_OFF + m*8 + b] = cc;
            cst -= cc * mnS[m][b];
        }
        ws[CONST_OFF + b] = cst;
    }
}

// ---------------- K_combine ----------------
__global__ __launch_bounds__(256) void k_comb(const float* __restrict__ ws,
                                              float* __restrict__ out)
{
    int t = blockIdx.x * 256 + threadIdx.x;
    if (t >= NB * (N_ENT/4)) return;
    int b = t / (N_ENT/4);
    int e = (t % (N_ENT/4)) * 4;
    const float* S = ws + S_OFF;
    float c0 = ws[C_OFF +  0 + b], c1 = ws[C_OFF +  8 + b], c2 = ws[C_OFF + 16 + b];
    float c3 = ws[C_OFF + 24 + b], c4 = ws[C_OFF + 32 + b];
    float cst = ws[CONST_OFF + b];
    float4 s0 = *(const float4*)(S + (0*8 + b)*N_ENT + e);
    float4 s1 = *(const float4*)(S + (1*8 + b)*N_ENT + e);
    float4 s2 = *(const float4*)(S + (2*8 + b)*N_ENT + e);
    float4 s3 = *(const float4*)(S + (3*8 + b)*N_ENT + e);
    float4 s4 = *(const float4*)(S + (4*8 + b)*N_ENT + e);
    float4 o4;
    o4.x = fmaf(c0,s0.x, fmaf(c1,s1.x, fmaf(c2,s2.x, fmaf(c3,s3.x, fmaf(c4,s4.x, cst)))));
    o4.y = fmaf(c0,s0.y, fmaf(c1,s1.y, fmaf(c2,s2.y, fmaf(c3,s3.y, fmaf(c4,s4.y, cst)))));
    o4.z = fmaf(c0,s0.z, fmaf(c1,s1.z, fmaf(c2,s2.z, fmaf(c3,s3.z, fmaf(c4,s4.z, cst)))));
    o4.w = fmaf(c0,s0.w, fmaf(c1,s1.w, fmaf(c2,s2.w, fmaf(c3,s3.w, fmaf(c4,s4.w, cst)))));
    *(float4*)(out + b*N_ENT + e) = o4;
}

extern "C" void kernel_launch(void* const* d_in, const int* in_sizes, int n_in,
                              void* d_out, int out_size, void* d_ws, size_t ws_size,
                              hipStream_t stream)
{
    const int*   batch  = (const int*)  d_in[0];
    const float* eemb   = (const float*)d_in[1];
    const float* remb   = (const float*)d_in[2];
    const float* ce_re  = (const float*)d_in[3];
    const float* ce_im  = (const float*)d_in[4];
    const float* cr_re  = (const float*)d_in[5];
    const float* cr_im  = (const float*)d_in[6];
    const float* de     = (const float*)d_in[7];
    const float* dr     = (const float*)d_in[8];
    const float* ke     = (const float*)d_in[9];
    const float* kr     = (const float*)d_in[10];
    const float* se_h   = (const float*)d_in[11];
    const float* se_t   = (const float*)d_in[12];
    const float* sr     = (const float*)d_in[13];
    const float* sr_inv = (const float*)d_in[14];
    const float* W0 = (const float*)d_in[15];
    const float* b0 = (const float*)d_in[16];
    const float* W1 = (const float*)d_in[17];
    const float* b1 = (const float*)d_in[18];
    const float* W2 = (const float*)d_in[19];
    const float* b2 = (const float*)d_in[20];
    const float* W3 = (const float*)d_in[21];
    const float* b3 = (const float*)d_in[22];
    float* ws  = (float*)d_ws;
    float* out = (float*)d_out;

    k_q    <<<8, 256, 0, stream>>>(batch, eemb, remb, ce_re, ce_im, cr_re, cr_im,
                                   de, dr, ke, kr, se_h, se_t, sr, sr_inv, ws);
    k_main <<<NBLK_MAIN, 256, 0, stream>>>(eemb, ce_re, ce_im, ke, de, se_h, se_t, ws);
    k_red  <<<40, 256, 0, stream>>>(ws);
    k_mlp  <<<1, 320, 0, stream>>>(W0, b0, W1, b1, W2, b2, W3, b3, ws);
    k_comb <<<(NB*(N_ENT/4) + 255)/256, 256, 0, stream>>>(ws, out);
}